// Round 1
// baseline (817.545 us; speedup 1.0000x reference)
//
#include <hip/hip_runtime.h>
#include <math.h>

#define Bq 2
#define NEG 16
#define Nn 10000
#define Ee 80000
#define Dd 128
#define NUM_REL 237
#define Ll 3
#define K_SEL 1000
#define BN (Bq*Nn)
#define EPSV 1e-5f
#define MAXACT 2048

// ---------------- workspace layout (bytes) ----------------
constexpr size_t HID_OFF   = 0;                                   // BN*D f32
constexpr size_t SCORE_OFF = HID_OFF   + (size_t)BN*Dd*4;         // BN f32
constexpr size_t CVEC_OFF  = SCORE_OFF + (size_t)BN*4;            // B*D f32
constexpr size_t HDR_OFF   = CVEC_OFF  + (size_t)Bq*Dd*4;         // 64 i32
constexpr size_t THR_OFF   = HDR_OFF   + 64*4;                    // B u64
constexpr size_t SEL_OFF   = THR_OFF   + Bq*8;                    // BN u32
constexpr size_t DEG_OFF   = SEL_OFF   + (size_t)BN*4;            // BN u32
constexpr size_t SLOT_OFF  = DEG_OFF   + (size_t)BN*4;            // BN i32
constexpr size_t CNT_OFF   = SLOT_OFF  + (size_t)BN*4;            // MAXACT u32
constexpr size_t SDEG_OFF  = CNT_OFF   + (size_t)MAXACT*4;        // MAXACT f32
constexpr size_t S1_OFF    = SDEG_OFF  + (size_t)MAXACT*4;        // MAXACT*D f32
constexpr size_t S2_OFF    = S1_OFF    + (size_t)MAXACT*Dd*4;
constexpr size_t MXB_OFF   = S2_OFF    + (size_t)MAXACT*Dd*4;     // MAXACT*D u32
constexpr size_t MNB_OFF   = MXB_OFF   + (size_t)MAXACT*Dd*4;
constexpr size_t BASE_OFF  = MNB_OFF   + (size_t)MAXACT*Dd*4;     // MAXACT*512 f32
constexpr size_t TBUF_OFF  = BASE_OFF  + (size_t)MAXACT*512*4;    // MAXACT*D f32
constexpr size_t ALIST_OFF = TBUF_OFF  + (size_t)MAXACT*Dd*4;     // MAXACT i32
constexpr size_t EDGE_OFF  = ALIST_OFF + (size_t)MAXACT*4;        // B*E*2 i32
constexpr size_t CTR_OFF   = EDGE_OFF  + (size_t)Bq*Ee*2*4;       // 16 u32

// ---------------- helpers ----------------
__device__ __forceinline__ unsigned encf(float f){
  unsigned u = __float_as_uint(f);
  return (u & 0x80000000u) ? ~u : (u | 0x80000000u);   // ascending orderable
}
__device__ __forceinline__ float decf(unsigned e){
  unsigned u = (e & 0x80000000u) ? (e & 0x7FFFFFFFu) : ~e;
  return __uint_as_float(u);
}
// 64-bit key: ascending key order == (score desc, index asc). Unique per node.
__device__ __forceinline__ unsigned long long make_key(float f, int i){
  unsigned d = ~encf(f);
  return ((unsigned long long)d << 32) | (unsigned)i;
}

// ---------------- kernels ----------------
__global__ void k_zero(float* hidden, float* score){
  int i = blockIdx.x*blockDim.x + threadIdx.x;
  if (i < BN*Dd) hidden[i] = 0.f;
  if (i < BN)    score[i]  = 0.f;
}

__global__ __launch_bounds__(256) void k_prep(
    const int* h_index, const int* r_index, const int* t_index,
    const float* hidden_states, const float* rel_embedding,
    const float* lin_W, const float* lin_b, const float* m1_W, const float* m1_b,
    const float* m2_W, const float* m2_b,
    int* hdr, float* cvec, float* hidden, float* score){
  __shared__ int sh_fh[Bq], sh_ft[Bq], sh_r0[Bq], sh_hsrc, sh_tsrc;
  __shared__ float s_relv[Bq][Dd], s_cvec[Bq][Dd], s_hv[Dd], s_x[Bq][Dd], s_p[Bq][Dd];
  int tid = threadIdx.x;
  if (tid == 0){
    for (int b=0;b<Bq;b++){
      bool eq = true;
      for (int j=1;j<NEG;j++) eq = eq && (h_index[b*NEG+j]==h_index[b*NEG]);
      int h0 = eq ? h_index[b*NEG] : t_index[b*NEG];
      int t0 = eq ? t_index[b*NEG] : h_index[b*NEG];
      int r0 = eq ? r_index[b*NEG] : r_index[b*NEG] + NUM_REL;
      sh_fh[b] = h0 + b*Nn; sh_ft[b] = t0 + b*Nn; sh_r0[b] = r0;
      hdr[0+b] = sh_fh[b]; hdr[2+b] = sh_ft[b];
      for (int j=0;j<NEG;j++){
        int tj = eq ? t_index[b*NEG+j] : h_index[b*NEG+j];
        hdr[4 + b*NEG + j] = tj + b*Nn;
      }
      if (b==0){ sh_hsrc = h0; sh_tsrc = t0; }
    }
  }
  __syncthreads();
  int b = tid >> 7, d = tid & 127;
  s_relv[b][d] = rel_embedding[(size_t)sh_r0[b]*Dd + d];
  if (b == 0) s_hv[d] = hidden_states[(size_t)sh_hsrc*Dd + d];
  __syncthreads();
  // cvec[b] = rel @ lin_W[D:2D,:] + lin_b
  float acc = lin_b[d];
  for (int k=0;k<Dd;k++) acc += s_relv[b][k]*lin_W[(Dd+k)*Dd + d];
  s_cvec[b][d] = acc; cvec[b*Dd+d] = acc;
  // boundary scatter: t first, h second (h overrides; same thread => ordered)
  hidden[(size_t)sh_ft[b]*Dd + d] = hidden_states[(size_t)sh_tsrc*Dd + d];
  hidden[(size_t)sh_fh[b]*Dd + d] = hidden_states[(size_t)sh_hsrc*Dd + d];
  __syncthreads();
  // initial score at head nodes
  float hv = s_hv[d];
  float heur = s_cvec[b][d];
  for (int k=0;k<Dd;k++) heur += s_hv[k]*lin_W[k*Dd + d];
  s_x[b][d] = heur * hv;
  __syncthreads();
  float a2 = m1_b[d];
  for (int k=0;k<Dd;k++) a2 += s_x[b][k]*m1_W[k*Dd + d];
  s_p[b][d] = fmaxf(a2, 0.f) * m2_W[d];
  __syncthreads();
  if (tid < Bq){
    float s = m2_b[0];
    for (int k=0;k<Dd;k++) s += s_p[tid][k];
    score[sh_fh[tid]] = s;
  }
}

__global__ void k_layer_init(unsigned* out_deg, unsigned* cnt, float* s1, float* s2,
                             unsigned* mxb, unsigned* mnb, unsigned* ctr){
  int i = blockIdx.x*blockDim.x + threadIdx.x;
  if (i < MAXACT*Dd){ s1[i]=0.f; s2[i]=0.f; mxb[i]=0u; mnb[i]=0xFFFFFFFFu; }
  if (i < BN) out_deg[i]=0u;
  if (i < MAXACT) cnt[i]=0u;
  if (i < 16) ctr[i]=0u;
}

// exact top-K via 64-bit radix select, one block per graph
__global__ __launch_bounds__(1024) void k_select(const float* score, unsigned long long* thr){
  int b = blockIdx.x;
  const float* sc = score + (size_t)b*Nn;
  __shared__ unsigned hist[256];
  __shared__ unsigned long long pref_sh;
  __shared__ unsigned kk_sh;
  int tid = threadIdx.x;
  if (tid==0){ pref_sh = 0ull; kk_sh = K_SEL; }
  __syncthreads();
  for (int pass=7; pass>=0; --pass){
    if (tid<256) hist[tid]=0u;
    __syncthreads();
    unsigned long long pref = pref_sh;
    for (int i=tid; i<Nn; i+=1024){
      unsigned long long key = make_key(sc[i], i);
      bool ok = (pass==7) || ((key >> (8*(pass+1))) == (pref >> (8*(pass+1))));
      if (ok) atomicAdd(&hist[(unsigned)(key >> (8*pass)) & 255u], 1u);
    }
    __syncthreads();
    if (tid < 256){
      unsigned kk = kk_sh;
      unsigned cum = 0;
      for (int i=0;i<tid;i++) cum += hist[i];
      unsigned h = hist[tid];
      if (cum < kk && kk <= cum + h){
        pref_sh |= ((unsigned long long)tid) << (8*pass);
        kk_sh = kk - cum;
      }
    }
    __syncthreads();
  }
  if (tid==0) thr[b] = pref_sh;
}

__global__ void k_mask(const float* score, const unsigned long long* thr, unsigned* sel){
  int v = blockIdx.x*blockDim.x + threadIdx.x;
  if (v >= BN) return;
  int b = v / Nn; int i = v - b*Nn;
  sel[v] = (make_key(score[v], i) <= thr[b]) ? 1u : 0u;
}

__global__ void k_degree(const int* ei, const unsigned* sel, unsigned* out_deg){
  int e = blockIdx.x*blockDim.x + threadIdx.x;
  if (e >= Ee) return;
  int s0 = ei[e];
  #pragma unroll
  for (int b=0;b<Bq;b++){
    int v = s0 + b*Nn;
    if (sel[v]) atomicAdd(&out_deg[v], 1u);
  }
}

__global__ void k_active(const unsigned* out_deg, int* node_slot, int* alist,
                         float* slot_deg, unsigned* ctr){
  int v = blockIdx.x*blockDim.x + threadIdx.x;
  if (v >= BN) return;
  unsigned dg = out_deg[v];
  if (dg > 0u){
    int slot = (int)atomicAdd(&ctr[0], 1u);
    alist[slot] = v; node_slot[v] = slot; slot_deg[slot] = (float)dg;
    atomicAdd((float*)&ctr[2], logf((float)dg + 1.0f));
  }
}

__global__ void k_edges(const int* ei, const unsigned* sel, const unsigned* out_deg,
                        const int* node_slot, int* edges, unsigned* cnt, unsigned* ctr){
  int e = blockIdx.x*blockDim.x + threadIdx.x;
  if (e >= Ee) return;
  int s0 = ei[e], d0 = ei[Ee + e];
  #pragma unroll
  for (int b=0;b<Bq;b++){
    int s = s0 + b*Nn, dv = d0 + b*Nn;
    if (sel[s]){
      if (out_deg[dv] > 0u){
        int slot = node_slot[dv];
        int j = (int)atomicAdd(&ctr[1], 1u);
        edges[2*j] = s; edges[2*j+1] = slot;
        atomicAdd(&cnt[slot], 1u);
      }
    }
  }
}

__global__ __launch_bounds__(128) void k_messages(
    const float* hidden, const int* edges, const int* alist,
    const float* preW, const float* preb,
    float* s1, float* s2, unsigned* mxb, unsigned* mnb, const unsigned* ctr){
  int ne = (int)ctr[1];
  int tid = threadIdx.x;
  __shared__ float hd[Dd], hs[Dd];
  for (int j = blockIdx.x; j < ne; j += gridDim.x){
    int s = edges[2*j], dslot = edges[2*j+1];
    int dv = alist[dslot];
    hd[tid] = hidden[(size_t)dv*Dd + tid];
    hs[tid] = hidden[(size_t)s*Dd + tid];
    __syncthreads();
    float acc = preb[tid];
    for (int k=0;k<Dd;k++){
      acc += hd[k]*preW[k*Dd + tid];
      acc += hs[k]*preW[(Dd+k)*Dd + tid];
    }
    atomicAdd(&s1[dslot*Dd + tid], acc);
    atomicAdd(&s2[dslot*Dd + tid], acc*acc);
    atomicMax(&mxb[dslot*Dd + tid], encf(acc));
    atomicMin(&mnb[dslot*Dd + tid], encf(acc));
    __syncthreads();
  }
}

__global__ __launch_bounds__(128) void k_finalize(
    const unsigned* cnt, const float* s1, const float* s2,
    const unsigned* mxb, const unsigned* mnb, float* base, const unsigned* ctr){
  int slot = blockIdx.x;
  if (slot >= (int)ctr[0]) return;
  int tid = threadIdx.x;
  unsigned c = cnt[slot];
  float denom = fmaxf((float)c, 1.0f);
  float mv = s1[slot*Dd+tid]/denom;
  float var = s2[slot*Dd+tid]/denom - mv*mv;
  var = fmaxf(var, 0.f);
  float sd = sqrtf(var + EPSV);
  float mx = (c>0u) ? decf(mxb[slot*Dd+tid]) : 0.f;
  float mn = (c>0u) ? decf(mnb[slot*Dd+tid]) : 0.f;
  float* bb = base + (size_t)slot*512;
  bb[tid] = mv; bb[128+tid] = mx; bb[256+tid] = mn; bb[384+tid] = sd;
}

__global__ __launch_bounds__(256) void k_post(
    const float* base, const float* slot_deg,
    const float* postW, const float* postb, float* tbuf, const unsigned* ctr){
  int na = (int)ctr[0];
  if (na == 0) return;
  float logsum = __uint_as_float(ctr[2]);
  float avg = (logsum + (float)(BN - na)*0.69314718056f) / (float)BN;
  __shared__ float lb[16*512];
  int tid = threadIdx.x;
  int c = tid & 127, rr = tid >> 7;
  int tiles = (na + 15) >> 4;
  for (int t = blockIdx.x; t < tiles; t += gridDim.x){
    __syncthreads();
    for (int idx = tid; idx < 16*512; idx += 256){
      int sl = idx >> 9, k = idx & 511;
      int slot = t*16 + sl;
      lb[idx] = (slot < na) ? base[(size_t)slot*512 + k] : 0.f;
    }
    __syncthreads();
    float a0[8], a1[8], a2[8];
    #pragma unroll
    for (int i=0;i<8;i++){ a0[i]=0.f; a1[i]=0.f; a2[i]=0.f; }
    for (int k=0;k<512;k++){
      float w0 = postW[(size_t)k*Dd + c];
      float w1 = postW[(size_t)(512+k)*Dd + c];
      float w2 = postW[(size_t)(1024+k)*Dd + c];
      #pragma unroll
      for (int i=0;i<8;i++){
        float bv = lb[(rr + 2*i)*512 + k];
        a0[i] += bv*w0; a1[i] += bv*w1; a2[i] += bv*w2;
      }
    }
    #pragma unroll
    for (int i=0;i<8;i++){
      int row = rr + 2*i; int slot = t*16 + row;
      if (slot < na){
        float dg = slot_deg[slot];
        float logd = logf(dg + 1.f);
        float al = logd/avg, be = avg/logd;
        tbuf[(size_t)slot*Dd + c] = a0[i] + al*a1[i] + be*a2[i] + postb[c];
      }
    }
  }
}

__global__ __launch_bounds__(128) void k_out_resid(
    const float* tbuf, const int* alist, const float* outW, const float* outb,
    float* hidden, const unsigned* ctr){
  int slot = blockIdx.x;
  if (slot >= (int)ctr[0]) return;
  int tid = threadIdx.x;
  __shared__ float tr[Dd];
  tr[tid] = tbuf[(size_t)slot*Dd + tid];
  __syncthreads();
  int v = alist[slot];
  float acc = outb[tid];
  for (int k=0;k<Dd;k++) acc += tr[k]*outW[k*Dd + tid];
  hidden[(size_t)v*Dd + tid] += acc;
}

__global__ __launch_bounds__(256) void k_score(
    const float* hidden, const float* cvec, const float* linW,
    const float* m1W, const float* m1b, const float* m2W, const float* m2b,
    float* score){
  __shared__ float sh[32*Dd];
  __shared__ float sx[32*Dd];
  __shared__ float sp[32*8];
  int tid = threadIdx.x;
  int nb = blockIdx.x * 32;
  for (int idx = tid; idx < 32*Dd; idx += 256)
    sh[idx] = hidden[(size_t)nb*Dd + idx];
  __syncthreads();
  int c = tid & 127, rr = tid >> 7;
  float acc[16];
  #pragma unroll
  for (int i=0;i<16;i++) acc[i]=0.f;
  for (int k=0;k<Dd;k++){
    float w = linW[k*Dd + c];
    #pragma unroll
    for (int i=0;i<16;i++) acc[i] += sh[(rr+2*i)*Dd + k]*w;
  }
  #pragma unroll
  for (int i=0;i<16;i++){
    int row = rr + 2*i;
    int b = ((nb + row) >= Nn) ? 1 : 0;
    float heur = acc[i] + cvec[b*Dd + c];
    sx[row*Dd + c] = heur * sh[row*Dd + c];
  }
  __syncthreads();
  #pragma unroll
  for (int i=0;i<16;i++) acc[i]=0.f;
  for (int k=0;k<Dd;k++){
    float w = m1W[k*Dd + c];
    #pragma unroll
    for (int i=0;i<16;i++) acc[i] += sx[(rr+2*i)*Dd + k]*w;
  }
  __syncthreads();            // all reads of sx done before overwrite
  float m2wc = m2W[c], m1bc = m1b[c];
  #pragma unroll
  for (int i=0;i<16;i++){
    int row = rr + 2*i;
    sx[row*Dd + c] = fmaxf(acc[i] + m1bc, 0.f) * m2wc;   // reuse as p
  }
  __syncthreads();
  int row = tid >> 3, j = tid & 7;
  float part = 0.f;
  for (int k = j*16; k < j*16+16; k++) part += sx[row*Dd + k];
  sp[row*8 + j] = part;
  __syncthreads();
  if (tid < 32){
    float s = m2b[0];
    for (int jj=0;jj<8;jj++) s += sp[tid*8 + jj];
    score[nb + tid] = s;
  }
}

__global__ void k_gather(const float* score, const int* hdr, float* out){
  int i = threadIdx.x;
  if (i < Bq*NEG) out[i] = score[hdr[4+i]];
}

// ---------------- launch ----------------
extern "C" void kernel_launch(void* const* d_in, const int* in_sizes, int n_in,
                              void* d_out, int out_size, void* d_ws, size_t ws_size,
                              hipStream_t stream){
  const int*   h_index       = (const int*)d_in[0];
  const int*   r_index       = (const int*)d_in[1];
  const int*   t_index       = (const int*)d_in[2];
  const float* hidden_states = (const float*)d_in[3];
  const int*   edge_index    = (const int*)d_in[4];
  const float* rel_embedding = (const float*)d_in[5];
  const float* lin_W  = (const float*)d_in[6];
  const float* lin_b  = (const float*)d_in[7];
  const float* m1_W   = (const float*)d_in[8];
  const float* m1_b   = (const float*)d_in[9];
  const float* m2_W   = (const float*)d_in[10];
  const float* m2_b   = (const float*)d_in[11];
  const float* pre_W  = (const float*)d_in[12];
  const float* pre_b  = (const float*)d_in[13];
  const float* post_W = (const float*)d_in[14];
  const float* post_b = (const float*)d_in[15];
  const float* out_W  = (const float*)d_in[16];
  const float* out_b  = (const float*)d_in[17];

  char* ws = (char*)d_ws;
  float*    hidden   = (float*)(ws + HID_OFF);
  float*    score    = (float*)(ws + SCORE_OFF);
  float*    cvec     = (float*)(ws + CVEC_OFF);
  int*      hdr      = (int*)(ws + HDR_OFF);
  unsigned long long* thr = (unsigned long long*)(ws + THR_OFF);
  unsigned* sel      = (unsigned*)(ws + SEL_OFF);
  unsigned* out_deg  = (unsigned*)(ws + DEG_OFF);
  int*      node_slot= (int*)(ws + SLOT_OFF);
  unsigned* cnt      = (unsigned*)(ws + CNT_OFF);
  float*    slot_deg = (float*)(ws + SDEG_OFF);
  float*    s1       = (float*)(ws + S1_OFF);
  float*    s2       = (float*)(ws + S2_OFF);
  unsigned* mxb      = (unsigned*)(ws + MXB_OFF);
  unsigned* mnb      = (unsigned*)(ws + MNB_OFF);
  float*    base     = (float*)(ws + BASE_OFF);
  float*    tbuf     = (float*)(ws + TBUF_OFF);
  int*      alist    = (int*)(ws + ALIST_OFF);
  int*      edges    = (int*)(ws + EDGE_OFF);
  unsigned* ctr      = (unsigned*)(ws + CTR_OFF);

  k_zero<<<(BN*Dd + 255)/256, 256, 0, stream>>>(hidden, score);
  k_prep<<<1, 256, 0, stream>>>(h_index, r_index, t_index, hidden_states, rel_embedding,
                                lin_W, lin_b, m1_W, m1_b, m2_W, m2_b,
                                hdr, cvec, hidden, score);
  for (int l = 0; l < Ll; ++l){
    const float* preWl  = pre_W  + (size_t)l*2*Dd*Dd;
    const float* prebl  = pre_b  + (size_t)l*Dd;
    const float* postWl = post_W + (size_t)l*12*Dd*Dd;
    const float* postbl = post_b + (size_t)l*Dd;
    const float* outWl  = out_W  + (size_t)l*Dd*Dd;
    const float* outbl  = out_b  + (size_t)l*Dd;

    k_layer_init<<<(MAXACT*Dd + 255)/256, 256, 0, stream>>>(out_deg, cnt, s1, s2, mxb, mnb, ctr);
    k_select<<<Bq, 1024, 0, stream>>>(score, thr);
    k_mask<<<(BN + 255)/256, 256, 0, stream>>>(score, thr, sel);
    k_degree<<<(Ee + 255)/256, 256, 0, stream>>>(edge_index, sel, out_deg);
    k_active<<<(BN + 255)/256, 256, 0, stream>>>(out_deg, node_slot, alist, slot_deg, ctr);
    k_edges<<<(Ee + 255)/256, 256, 0, stream>>>(edge_index, sel, out_deg, node_slot, edges, cnt, ctr);
    k_messages<<<1024, 128, 0, stream>>>(hidden, edges, alist, preWl, prebl, s1, s2, mxb, mnb, ctr);
    k_finalize<<<MAXACT, 128, 0, stream>>>(cnt, s1, s2, mxb, mnb, base, ctr);
    k_post<<<128, 256, 0, stream>>>(base, slot_deg, postWl, postbl, tbuf, ctr);
    k_out_resid<<<MAXACT, 128, 0, stream>>>(tbuf, alist, outWl, outbl, hidden, ctr);
    k_score<<<BN/32, 256, 0, stream>>>(hidden, cvec, lin_W, m1_W, m1_b, m2_W, m2_b, score);
  }
  k_gather<<<1, 64, 0, stream>>>(score, hdr, (float*)d_out);
}

// Round 2
// 653.116 us; speedup vs baseline: 1.2518x; 1.2518x over previous
//
#include <hip/hip_runtime.h>
#include <math.h>

#define Bq 2
#define NEG 16
#define Nn 10000
#define Ee 80000
#define Dd 128
#define NUM_REL 237
#define Ll 3
#define K_SEL 1000
#define BN (Bq*Nn)
#define EPSV 1e-5f
#define MAXACT 2048
#define MAXTOUCH 8192
#define LN2F 0.69314718056f

// ---------------- workspace layout (bytes) ----------------
constexpr size_t HID_OFF   = 0;                                   // BN*D f32
constexpr size_t SCORE_OFF = HID_OFF   + (size_t)BN*Dd*4;         // BN f32
constexpr size_t CVEC_OFF  = SCORE_OFF + (size_t)BN*4;            // B*D f32
constexpr size_t HDR_OFF   = CVEC_OFF  + (size_t)Bq*Dd*4;         // 64 i32
constexpr size_t THR_OFF   = HDR_OFF   + 64*4;                    // B u64
constexpr size_t SEL_OFF   = THR_OFF   + Bq*8;                    // BN u32
constexpr size_t DEG_OFF   = SEL_OFF   + (size_t)BN*4;            // BN u32
constexpr size_t SLOT_OFF  = DEG_OFF   + (size_t)BN*4;            // BN i32
constexpr size_t CNT_OFF   = SLOT_OFF  + (size_t)BN*4;            // MAXACT u32
constexpr size_t SDEG_OFF  = CNT_OFF   + (size_t)MAXACT*4;        // MAXACT f32
constexpr size_t S1_OFF    = SDEG_OFF  + (size_t)MAXACT*4;        // MAXACT*D f32
constexpr size_t S2_OFF    = S1_OFF    + (size_t)MAXACT*Dd*4;
constexpr size_t MXB_OFF   = S2_OFF    + (size_t)MAXACT*Dd*4;     // MAXACT*D u32
constexpr size_t MNB_OFF   = MXB_OFF   + (size_t)MAXACT*Dd*4;
constexpr size_t TPART_OFF = MNB_OFF   + (size_t)MAXACT*Dd*4;     // 4*MAXACT*D f32
constexpr size_t ALIST_OFF = TPART_OFF + (size_t)4*MAXACT*Dd*4;   // MAXACT i32
constexpr size_t FLAG_OFF  = ALIST_OFF + (size_t)MAXACT*4;        // BN u32
constexpr size_t TLIST_OFF = FLAG_OFF  + (size_t)BN*4;            // MAXTOUCH i32
constexpr size_t EDGE_OFF  = TLIST_OFF + (size_t)MAXTOUCH*4;      // B*E*2 i32
constexpr size_t CTR_OFF   = EDGE_OFF  + (size_t)Bq*Ee*2*4;       // 16 u32
// ctr[0]=na  ctr[1]=ne  ctr[2]=sum(log(deg+1)) as f32 bits  ctr[3]=ntouched

// ---------------- helpers ----------------
__device__ __forceinline__ unsigned encf(float f){
  unsigned u = __float_as_uint(f);
  return (u & 0x80000000u) ? ~u : (u | 0x80000000u);
}
__device__ __forceinline__ float decf(unsigned e){
  unsigned u = (e & 0x80000000u) ? (e & 0x7FFFFFFFu) : ~e;
  return __uint_as_float(u);
}
__device__ __forceinline__ unsigned long long make_key(float f, int i){
  unsigned d = ~encf(f);
  return ((unsigned long long)d << 32) | (unsigned)i;
}

// ---------------- kernels ----------------
__global__ void k_zero(float* hidden, unsigned* flag){
  int i = blockIdx.x*blockDim.x + threadIdx.x;
  if (i < BN*Dd/4) ((float4*)hidden)[i] = make_float4(0.f,0.f,0.f,0.f);
  if (i < BN) flag[i] = 0u;
}

__global__ __launch_bounds__(256) void k_prep(
    const int* h_index, const int* r_index, const int* t_index,
    const float* hidden_states, const float* rel_embedding,
    const float* lin_W, const float* lin_b, const float* m1_W, const float* m1_b,
    const float* m2_W, const float* m2_b,
    int* hdr, float* cvec, float* hidden, float* score,
    unsigned* flag, int* tlist, unsigned* ctr){
  __shared__ int sh_fh[Bq], sh_ft[Bq], sh_r0[Bq], sh_hsrc, sh_tsrc;
  __shared__ float s_relv[Bq][Dd], s_cvec[Bq][Dd], s_hv[Dd], s_x[Bq][Dd], s_p[Bq][Dd];
  __shared__ float s_s0[Dd];
  __shared__ float sc0_sh;
  int tid = threadIdx.x;
  if (tid == 0){
    int n = 0;
    for (int b=0;b<Bq;b++){
      bool eq = true;
      for (int j=1;j<NEG;j++) eq = eq && (h_index[b*NEG+j]==h_index[b*NEG]);
      int h0 = eq ? h_index[b*NEG] : t_index[b*NEG];
      int t0 = eq ? t_index[b*NEG] : h_index[b*NEG];
      int r0 = eq ? r_index[b*NEG] : r_index[b*NEG] + NUM_REL;
      sh_fh[b] = h0 + b*Nn; sh_ft[b] = t0 + b*Nn; sh_r0[b] = r0;
      hdr[0+b] = sh_fh[b]; hdr[2+b] = sh_ft[b];
      for (int j=0;j<NEG;j++){
        int tj = eq ? t_index[b*NEG+j] : h_index[b*NEG+j];
        hdr[4 + b*NEG + j] = tj + b*Nn;
      }
      if (b==0){ sh_hsrc = h0; sh_tsrc = t0; }
      // touched list init
      if (!flag[sh_ft[b]]){ flag[sh_ft[b]] = 1u; tlist[n++] = sh_ft[b]; }
      if (!flag[sh_fh[b]]){ flag[sh_fh[b]] = 1u; tlist[n++] = sh_fh[b]; }
    }
    ctr[3] = (unsigned)n;
  }
  __syncthreads();
  int b = tid >> 7, d = tid & 127;
  s_relv[b][d] = rel_embedding[(size_t)sh_r0[b]*Dd + d];
  if (b == 0){
    s_hv[d] = hidden_states[(size_t)sh_hsrc*Dd + d];
    s_s0[d] = fmaxf(m1_b[d], 0.f) * m2_W[d];   // untouched-node score terms
  }
  __syncthreads();
  if (tid == 0){
    float s = m2_b[0];
    for (int k=0;k<Dd;k++) s += s_s0[k];
    sc0_sh = s;
  }
  // cvec[b] = rel @ lin_W[D:2D,:] + lin_b
  float acc = lin_b[d];
  for (int k=0;k<Dd;k++) acc += s_relv[b][k]*lin_W[(Dd+k)*Dd + d];
  s_cvec[b][d] = acc; cvec[b*Dd+d] = acc;
  // boundary scatter: t first, h second (h overrides; same thread => ordered)
  hidden[(size_t)sh_ft[b]*Dd + d] = hidden_states[(size_t)sh_tsrc*Dd + d];
  hidden[(size_t)sh_fh[b]*Dd + d] = hidden_states[(size_t)sh_hsrc*Dd + d];
  __syncthreads();
  // fill score with untouched constant
  float sc0 = sc0_sh;
  for (int i = tid; i < BN; i += 256) score[i] = sc0;
  // initial score at head nodes
  float hv = s_hv[d];
  float heur = s_cvec[b][d];
  for (int k=0;k<Dd;k++) heur += s_hv[k]*lin_W[k*Dd + d];
  s_x[b][d] = heur * hv;
  __syncthreads();
  float a2 = m1_b[d];
  for (int k=0;k<Dd;k++) a2 += s_x[b][k]*m1_W[k*Dd + d];
  s_p[b][d] = fmaxf(a2, 0.f) * m2_W[d];
  __syncthreads();
  if (tid < Bq){
    float s = m2_b[0];
    for (int k=0;k<Dd;k++) s += s_p[tid][k];
    score[sh_fh[tid]] = s;
  }
}

// exact top-K via 64-bit radix select, one block per graph
__global__ __launch_bounds__(1024) void k_select(const float* score, unsigned long long* thr){
  int b = blockIdx.x;
  const float* sc = score + (size_t)b*Nn;
  __shared__ unsigned hist[256];
  __shared__ unsigned long long pref_sh;
  __shared__ unsigned kk_sh;
  int tid = threadIdx.x;
  if (tid==0){ pref_sh = 0ull; kk_sh = K_SEL; }
  __syncthreads();
  for (int pass=7; pass>=0; --pass){
    if (tid<256) hist[tid]=0u;
    __syncthreads();
    unsigned long long pref = pref_sh;
    for (int i=tid; i<Nn; i+=1024){
      unsigned long long key = make_key(sc[i], i);
      bool ok = (pass==7) || ((key >> (8*(pass+1))) == (pref >> (8*(pass+1))));
      if (ok) atomicAdd(&hist[(unsigned)(key >> (8*pass)) & 255u], 1u);
    }
    __syncthreads();
    if (tid < 256){
      unsigned kk = kk_sh;
      unsigned cum = 0;
      for (int i=0;i<tid;i++) cum += hist[i];
      unsigned h = hist[tid];
      if (cum < kk && kk <= cum + h){
        pref_sh |= ((unsigned long long)tid) << (8*pass);
        kk_sh = kk - cum;
      }
    }
    __syncthreads();
  }
  if (tid==0) thr[b] = pref_sh;
}

// mask + all per-layer zeroing fused
__global__ void k_mask(const float* score, const unsigned long long* thr, unsigned* sel,
                       unsigned* out_deg, float* s1, float* s2,
                       unsigned* mxb, unsigned* mnb, unsigned* cnt, unsigned* ctr){
  int i = blockIdx.x*blockDim.x + threadIdx.x;
  if (i < BN){
    int b = i / Nn; int v = i - b*Nn;
    sel[i] = (make_key(score[i], v) <= thr[b]) ? 1u : 0u;
    out_deg[i] = 0u;
  }
  if (i < MAXACT*Dd){ s1[i]=0.f; s2[i]=0.f; mxb[i]=0u; mnb[i]=0xFFFFFFFFu; }
  if (i < MAXACT) cnt[i]=0u;
  if (i < 3) ctr[i]=0u;      // keep ctr[3] (touched count)
}

__global__ void k_degree(const int* ei, const unsigned* sel, unsigned* out_deg){
  int e = blockIdx.x*blockDim.x + threadIdx.x;
  if (e >= Ee) return;
  int s0 = ei[e];
  #pragma unroll
  for (int b=0;b<Bq;b++){
    int v = s0 + b*Nn;
    if (sel[v]) atomicAdd(&out_deg[v], 1u);
  }
}

__global__ void k_active(const unsigned* out_deg, int* node_slot, int* alist,
                         float* slot_deg, unsigned* ctr, unsigned* flag, int* tlist){
  int v = blockIdx.x*blockDim.x + threadIdx.x;
  if (v >= BN) return;
  unsigned dg = out_deg[v];
  if (dg > 0u){
    int slot = (int)atomicAdd(&ctr[0], 1u);
    alist[slot] = v; node_slot[v] = slot; slot_deg[slot] = (float)dg;
    atomicAdd((float*)&ctr[2], logf((float)dg + 1.0f));
    if (atomicExch(&flag[v], 1u) == 0u){
      int p = (int)atomicAdd(&ctr[3], 1u);
      tlist[p] = v;
    }
  }
}

__global__ void k_edges(const int* ei, const unsigned* sel, const unsigned* out_deg,
                        const int* node_slot, int* edges, unsigned* cnt, unsigned* ctr){
  int e = blockIdx.x*blockDim.x + threadIdx.x;
  if (e >= Ee) return;
  int s0 = ei[e], d0 = ei[Ee + e];
  #pragma unroll
  for (int b=0;b<Bq;b++){
    int s = s0 + b*Nn, dv = d0 + b*Nn;
    if (sel[s] && out_deg[dv] > 0u){
      int slot = node_slot[dv];
      int j = (int)atomicAdd(&ctr[1], 1u);
      edges[2*j] = s; edges[2*j+1] = slot;
      atomicAdd(&cnt[slot], 1u);
    }
  }
}

// 4 edges per block: amortize preW streaming
__global__ __launch_bounds__(128) void k_messages(
    const float* hidden, const int* edges, const int* alist,
    const float* preW, const float* preb,
    float* s1, float* s2, unsigned* mxb, unsigned* mnb, const unsigned* ctr){
  int ne = (int)ctr[1];
  int tid = threadIdx.x;
  __shared__ float sd[4][Dd], ss[4][Dd];
  __shared__ int dsl[4];
  float pb = preb[tid];
  for (int j0 = blockIdx.x*4; j0 < ne; j0 += gridDim.x*4){
    int nv = ne - j0; if (nv > 4) nv = 4;
    if (tid < 4){
      int j = j0 + ((tid < nv) ? tid : 0);
      dsl[tid] = edges[2*j+1];
    }
    #pragma unroll
    for (int e=0;e<4;e++){
      int j = j0 + ((e < nv) ? e : 0);
      int s = edges[2*j];
      int dv = alist[edges[2*j+1]];
      sd[e][tid] = hidden[(size_t)dv*Dd + tid];
      ss[e][tid] = hidden[(size_t)s*Dd + tid];
    }
    __syncthreads();
    float a[4] = {pb, pb, pb, pb};
    for (int k=0;k<Dd;k++){
      float w0 = preW[k*Dd + tid];
      float w1 = preW[(Dd+k)*Dd + tid];
      #pragma unroll
      for (int e=0;e<4;e++) a[e] += sd[e][k]*w0 + ss[e][k]*w1;
    }
    for (int e=0;e<nv;e++){
      int dslot = dsl[e];
      atomicAdd(&s1[dslot*Dd + tid], a[e]);
      atomicAdd(&s2[dslot*Dd + tid], a[e]*a[e]);
      atomicMax(&mxb[dslot*Dd + tid], encf(a[e]));
      atomicMin(&mnb[dslot*Dd + tid], encf(a[e]));
    }
    __syncthreads();
  }
}

// fused finalize+post GEMM: grid = 64 row-tiles x 4 k-chunks x 2 col-halves
__global__ __launch_bounds__(256) void k_post(
    const unsigned* cnt, const float* s1, const float* s2,
    const unsigned* mxb, const unsigned* mnb, const float* slot_deg,
    const float* postW, float* tpart, const unsigned* ctr){
  int na = (int)ctr[0];
  int bid = blockIdx.x;
  int tile = bid & 63, ch = (bid >> 6) & 3, half = bid >> 8;
  if (tile*32 >= na) return;
  float logsum = __uint_as_float(ctr[2]);
  float avg = (logsum + (float)(BN - na)*LN2F) / (float)BN;
  __shared__ float lb[32*Dd];
  __shared__ float sden[32];
  __shared__ unsigned shas[32];
  int tid = threadIdx.x;
  if (tid < 32){
    unsigned c = cnt[tile*32 + tid];
    sden[tid] = fmaxf((float)c, 1.0f);
    shas[tid] = c;
  }
  __syncthreads();
  for (int idx = tid; idx < 32*Dd; idx += 256){
    int sl = idx >> 7, kk = idx & 127;
    int gi = (tile*32 + sl)*Dd + kk;
    float den = sden[sl];
    float val;
    if (ch == 0)      val = s1[gi]/den;
    else if (ch == 1) val = shas[sl] ? decf(mxb[gi]) : 0.f;
    else if (ch == 2) val = shas[sl] ? decf(mnb[gi]) : 0.f;
    else {
      float mv = s1[gi]/den;
      float var = s2[gi]/den - mv*mv;
      val = sqrtf(fmaxf(var, 0.f) + EPSV);
    }
    lb[idx] = val;
  }
  __syncthreads();
  int cg = tid & 15, rg = tid >> 4;           // 64 cols (cg*4), 32 rows (rg*2)
  int ccol0 = half*64 + cg*4;
  float a0[2][4], a1[2][4], a2[2][4];
  #pragma unroll
  for (int i=0;i<2;i++)
    #pragma unroll
    for (int j=0;j<4;j++){ a0[i][j]=0.f; a1[i][j]=0.f; a2[i][j]=0.f; }
  for (int k4=0; k4<32; ++k4){
    float4 av[2];
    #pragma unroll
    for (int i=0;i<2;i++) av[i] = ((float4*)lb)[(rg*2+i)*32 + k4];
    #pragma unroll
    for (int j=0;j<4;j++){
      int krow = ch*128 + k4*4 + j;
      const float* wp = postW + (size_t)krow*Dd + ccol0;
      float4 w0 = *(const float4*)(wp);
      float4 w1 = *(const float4*)(wp + 512*Dd);
      float4 w2 = *(const float4*)(wp + 1024*Dd);
      #pragma unroll
      for (int i=0;i<2;i++){
        float a = (&av[i].x)[j];
        a0[i][0] += a*w0.x; a0[i][1] += a*w0.y; a0[i][2] += a*w0.z; a0[i][3] += a*w0.w;
        a1[i][0] += a*w1.x; a1[i][1] += a*w1.y; a1[i][2] += a*w1.z; a1[i][3] += a*w1.w;
        a2[i][0] += a*w2.x; a2[i][1] += a*w2.y; a2[i][2] += a*w2.z; a2[i][3] += a*w2.w;
      }
    }
  }
  #pragma unroll
  for (int i=0;i<2;i++){
    int slot = tile*32 + rg*2 + i;
    if (slot < na){
      float dg = slot_deg[slot];
      float logd = logf(dg + 1.f);
      float al = logd/avg, be = avg/logd;
      float4 r;
      r.x = a0[i][0] + al*a1[i][0] + be*a2[i][0];
      r.y = a0[i][1] + al*a1[i][1] + be*a2[i][1];
      r.z = a0[i][2] + al*a1[i][2] + be*a2[i][2];
      r.w = a0[i][3] + al*a1[i][3] + be*a2[i][3];
      *(float4*)(tpart + (size_t)ch*MAXACT*Dd + (size_t)slot*Dd + ccol0) = r;
    }
  }
}

__global__ __launch_bounds__(128) void k_out_resid(
    const float* tpart, const int* alist, const float* outW, const float* outb,
    const float* postb, float* hidden, const unsigned* ctr){
  int slot = blockIdx.x;
  if (slot >= (int)ctr[0]) return;
  int tid = threadIdx.x;
  __shared__ float tr[Dd];
  size_t o = (size_t)slot*Dd + tid;
  tr[tid] = tpart[o] + tpart[(size_t)MAXACT*Dd + o] + tpart[(size_t)2*MAXACT*Dd + o]
          + tpart[(size_t)3*MAXACT*Dd + o] + postb[tid];
  __syncthreads();
  int v = alist[slot];
  float acc = outb[tid];
  for (int k4=0;k4<32;k4++){
    float4 t4 = *(float4*)&tr[k4*4];
    acc += t4.x*outW[(k4*4+0)*Dd + tid];
    acc += t4.y*outW[(k4*4+1)*Dd + tid];
    acc += t4.z*outW[(k4*4+2)*Dd + tid];
    acc += t4.w*outW[(k4*4+3)*Dd + tid];
  }
  hidden[(size_t)v*Dd + tid] += acc;
}

// score only touched nodes; 32 rows/block, 4x4 register tile
__global__ __launch_bounds__(256) void k_score(
    const float* hidden, const float* cvec, const float* linW,
    const float* m1W, const float* m1b, const float* m2W, const float* m2b,
    const int* tlist, const unsigned* ctr, float* score){
  int nt = (int)ctr[3];
  int nb = blockIdx.x * 32;
  if (nb >= nt) return;
  __shared__ float sh[32*Dd];
  __shared__ float sx[32*Dd];
  __shared__ float sc[2*Dd];
  __shared__ int   sv[32];
  __shared__ float red[32*33];
  int tid = threadIdx.x;
  if (tid < 32){
    int idx = nb + tid;
    sv[tid] = (idx < nt) ? tlist[idx] : tlist[nb];
  }
  sc[tid] = cvec[tid];
  __syncthreads();
  for (int q = tid; q < 32*32; q += 256){
    int row = q >> 5, f4 = q & 31;
    ((float4*)sh)[row*32 + f4] = ((const float4*)(hidden + (size_t)sv[row]*Dd))[f4];
  }
  __syncthreads();
  int cg = tid & 31, rg = tid >> 5;  // cols cg*4, rows rg*4..+3
  int c0 = cg*4;
  float acc[4][4];
  #pragma unroll
  for (int i=0;i<4;i++){ acc[i][0]=0.f; acc[i][1]=0.f; acc[i][2]=0.f; acc[i][3]=0.f; }
  for (int k4=0;k4<32;k4++){
    float4 av[4];
    #pragma unroll
    for (int i=0;i<4;i++) av[i] = ((float4*)sh)[(rg*4+i)*32 + k4];
    #pragma unroll
    for (int j=0;j<4;j++){
      float4 w = *(const float4*)(linW + (size_t)(k4*4+j)*Dd + c0);
      #pragma unroll
      for (int i=0;i<4;i++){
        float a = (&av[i].x)[j];
        acc[i][0] += a*w.x; acc[i][1] += a*w.y; acc[i][2] += a*w.z; acc[i][3] += a*w.w;
      }
    }
  }
  #pragma unroll
  for (int i=0;i<4;i++){
    int row = rg*4 + i;
    int bb = (sv[row] >= Nn) ? 1 : 0;
    float4 cv = *(float4*)&sc[bb*Dd + c0];
    float4 hv = ((float4*)sh)[row*32 + cg];
    float4 x;
    x.x = (acc[i][0] + cv.x)*hv.x;
    x.y = (acc[i][1] + cv.y)*hv.y;
    x.z = (acc[i][2] + cv.z)*hv.z;
    x.w = (acc[i][3] + cv.w)*hv.w;
    ((float4*)sx)[row*32 + cg] = x;
  }
  __syncthreads();
  #pragma unroll
  for (int i=0;i<4;i++){ acc[i][0]=0.f; acc[i][1]=0.f; acc[i][2]=0.f; acc[i][3]=0.f; }
  for (int k4=0;k4<32;k4++){
    float4 av[4];
    #pragma unroll
    for (int i=0;i<4;i++) av[i] = ((float4*)sx)[(rg*4+i)*32 + k4];
    #pragma unroll
    for (int j=0;j<4;j++){
      float4 w = *(const float4*)(m1W + (size_t)(k4*4+j)*Dd + c0);
      #pragma unroll
      for (int i=0;i<4;i++){
        float a = (&av[i].x)[j];
        acc[i][0] += a*w.x; acc[i][1] += a*w.y; acc[i][2] += a*w.z; acc[i][3] += a*w.w;
      }
    }
  }
  float4 mb = *(const float4*)(m1b + c0);
  float4 mw = *(const float4*)(m2W + c0);
  #pragma unroll
  for (int i=0;i<4;i++){
    float p0 = fmaxf(acc[i][0]+mb.x, 0.f)*mw.x;
    float p1 = fmaxf(acc[i][1]+mb.y, 0.f)*mw.y;
    float p2 = fmaxf(acc[i][2]+mb.z, 0.f)*mw.z;
    float p3 = fmaxf(acc[i][3]+mb.w, 0.f)*mw.w;
    red[(rg*4+i)*33 + cg] = p0+p1+p2+p3;
  }
  __syncthreads();
  if (tid < 32){
    float s = m2b[0];
    for (int g=0; g<32; g++) s += red[tid*33 + g];
    if (nb + tid < nt) score[sv[tid]] = s;
  }
}

__global__ void k_gather(const float* score, const int* hdr, float* out){
  int i = threadIdx.x;
  if (i < Bq*NEG) out[i] = score[hdr[4+i]];
}

// ---------------- launch ----------------
extern "C" void kernel_launch(void* const* d_in, const int* in_sizes, int n_in,
                              void* d_out, int out_size, void* d_ws, size_t ws_size,
                              hipStream_t stream){
  const int*   h_index       = (const int*)d_in[0];
  const int*   r_index       = (const int*)d_in[1];
  const int*   t_index       = (const int*)d_in[2];
  const float* hidden_states = (const float*)d_in[3];
  const int*   edge_index    = (const int*)d_in[4];
  const float* rel_embedding = (const float*)d_in[5];
  const float* lin_W  = (const float*)d_in[6];
  const float* lin_b  = (const float*)d_in[7];
  const float* m1_W   = (const float*)d_in[8];
  const float* m1_b   = (const float*)d_in[9];
  const float* m2_W   = (const float*)d_in[10];
  const float* m2_b   = (const float*)d_in[11];
  const float* pre_W  = (const float*)d_in[12];
  const float* pre_b  = (const float*)d_in[13];
  const float* post_W = (const float*)d_in[14];
  const float* post_b = (const float*)d_in[15];
  const float* out_W  = (const float*)d_in[16];
  const float* out_b  = (const float*)d_in[17];

  char* ws = (char*)d_ws;
  float*    hidden   = (float*)(ws + HID_OFF);
  float*    score    = (float*)(ws + SCORE_OFF);
  float*    cvec     = (float*)(ws + CVEC_OFF);
  int*      hdr      = (int*)(ws + HDR_OFF);
  unsigned long long* thr = (unsigned long long*)(ws + THR_OFF);
  unsigned* sel      = (unsigned*)(ws + SEL_OFF);
  unsigned* out_deg  = (unsigned*)(ws + DEG_OFF);
  int*      node_slot= (int*)(ws + SLOT_OFF);
  unsigned* cnt      = (unsigned*)(ws + CNT_OFF);
  float*    slot_deg = (float*)(ws + SDEG_OFF);
  float*    s1       = (float*)(ws + S1_OFF);
  float*    s2       = (float*)(ws + S2_OFF);
  unsigned* mxb      = (unsigned*)(ws + MXB_OFF);
  unsigned* mnb      = (unsigned*)(ws + MNB_OFF);
  float*    tpart    = (float*)(ws + TPART_OFF);
  int*      alist    = (int*)(ws + ALIST_OFF);
  unsigned* flag     = (unsigned*)(ws + FLAG_OFF);
  int*      tlist    = (int*)(ws + TLIST_OFF);
  int*      edges    = (int*)(ws + EDGE_OFF);
  unsigned* ctr      = (unsigned*)(ws + CTR_OFF);

  k_zero<<<(BN*Dd/4 + 255)/256, 256, 0, stream>>>(hidden, flag);
  k_prep<<<1, 256, 0, stream>>>(h_index, r_index, t_index, hidden_states, rel_embedding,
                                lin_W, lin_b, m1_W, m1_b, m2_W, m2_b,
                                hdr, cvec, hidden, score, flag, tlist, ctr);
  for (int l = 0; l < Ll; ++l){
    const float* preWl  = pre_W  + (size_t)l*2*Dd*Dd;
    const float* prebl  = pre_b  + (size_t)l*Dd;
    const float* postWl = post_W + (size_t)l*12*Dd*Dd;
    const float* postbl = post_b + (size_t)l*Dd;
    const float* outWl  = out_W  + (size_t)l*Dd*Dd;
    const float* outbl  = out_b  + (size_t)l*Dd;

    k_select<<<Bq, 1024, 0, stream>>>(score, thr);
    k_mask<<<(MAXACT*Dd + 255)/256, 256, 0, stream>>>(score, thr, sel, out_deg,
                                                      s1, s2, mxb, mnb, cnt, ctr);
    k_degree<<<(Ee + 255)/256, 256, 0, stream>>>(edge_index, sel, out_deg);
    k_active<<<(BN + 255)/256, 256, 0, stream>>>(out_deg, node_slot, alist, slot_deg,
                                                 ctr, flag, tlist);
    k_edges<<<(Ee + 255)/256, 256, 0, stream>>>(edge_index, sel, out_deg, node_slot,
                                                edges, cnt, ctr);
    k_messages<<<512, 128, 0, stream>>>(hidden, edges, alist, preWl, prebl,
                                        s1, s2, mxb, mnb, ctr);
    k_post<<<512, 256, 0, stream>>>(cnt, s1, s2, mxb, mnb, slot_deg, postWl, tpart, ctr);
    k_out_resid<<<MAXACT, 128, 0, stream>>>(tpart, alist, outWl, outbl, postbl, hidden, ctr);
    k_score<<<MAXTOUCH/32, 256, 0, stream>>>(hidden, cvec, lin_W, m1_W, m1_b, m2_W, m2_b,
                                             tlist, ctr, score);
  }
  k_gather<<<1, 64, 0, stream>>>(score, hdr, (float*)d_out);
}

// Round 3
// 514.426 us; speedup vs baseline: 1.5892x; 1.2696x over previous
//
#include <hip/hip_runtime.h>
#include <math.h>

#define Bq 2
#define NEG 16
#define Nn 10000
#define Ee 80000
#define Dd 128
#define NUM_REL 237
#define Ll 3
#define K_SEL 1000
#define BN (Bq*Nn)
#define EPSV 1e-5f
#define MAXACT 2048
#define MAXTOUCH 8192
#define SELCAP 3328
#define LN2F 0.69314718056f

// ---------------- workspace layout (bytes) ----------------
constexpr size_t HID_OFF   = 0;                                   // BN*D f32
constexpr size_t SCORE_OFF = HID_OFF   + (size_t)BN*Dd*4;         // BN f32
constexpr size_t CVEC_OFF  = SCORE_OFF + (size_t)BN*4;            // B*D f32
constexpr size_t HDR_OFF   = CVEC_OFF  + (size_t)Bq*Dd*4;         // 64 i32
constexpr size_t THR_OFF   = HDR_OFF   + 64*4;                    // B u64
constexpr size_t SEL_OFF   = THR_OFF   + Bq*8;                    // BN u32
constexpr size_t DEG_OFF   = SEL_OFF   + (size_t)BN*4;            // BN u32
constexpr size_t SLOT_OFF  = DEG_OFF   + (size_t)BN*4;            // BN i32
constexpr size_t CNT_OFF   = SLOT_OFF  + (size_t)BN*4;            // MAXACT u32
constexpr size_t SDEG_OFF  = CNT_OFF   + (size_t)MAXACT*4;        // MAXACT f32
constexpr size_t S1_OFF    = SDEG_OFF  + (size_t)MAXACT*4;        // MAXACT*D f32
constexpr size_t S2_OFF    = S1_OFF    + (size_t)MAXACT*Dd*4;
constexpr size_t MXB_OFF   = S2_OFF    + (size_t)MAXACT*Dd*4;     // MAXACT*D u32
constexpr size_t MNB_OFF   = MXB_OFF   + (size_t)MAXACT*Dd*4;
constexpr size_t TPART_OFF = MNB_OFF   + (size_t)MAXACT*Dd*4;     // 4*MAXACT*D f32
constexpr size_t ALIST_OFF = TPART_OFF + (size_t)4*MAXACT*Dd*4;   // MAXACT i32
constexpr size_t FLAG_OFF  = ALIST_OFF + (size_t)MAXACT*4;        // BN u32
constexpr size_t TLIST_OFF = FLAG_OFF  + (size_t)BN*4;            // MAXTOUCH i32
constexpr size_t EDGE_OFF  = TLIST_OFF + (size_t)MAXTOUCH*4;      // B*E*2 i32
constexpr size_t CTR_OFF   = EDGE_OFF  + (size_t)Bq*Ee*2*4;       // 16 u32
// ctr[0]=na ctr[1]=ne ctr[2]=sum(log(deg+1)) f32-bits ctr[3]=ntouched ctr[4]=sc0 f32-bits

// ---------------- helpers ----------------
__device__ __forceinline__ unsigned encf(float f){
  unsigned u = __float_as_uint(f);
  return (u & 0x80000000u) ? ~u : (u | 0x80000000u);
}
__device__ __forceinline__ float decf(unsigned e){
  unsigned u = (e & 0x80000000u) ? (e & 0x7FFFFFFFu) : ~e;
  return __uint_as_float(u);
}
__device__ __forceinline__ unsigned long long make_key(float f, int i){
  unsigned d = ~encf(f);
  return ((unsigned long long)d << 32) | (unsigned)i;
}

// ---------------- kernels ----------------
__global__ void k_zero(float* hidden, unsigned* flag){
  int i = blockIdx.x*blockDim.x + threadIdx.x;
  if (i < BN*Dd/4) ((float4*)hidden)[i] = make_float4(0.f,0.f,0.f,0.f);
  if (i < BN) flag[i] = 0u;
}

__global__ __launch_bounds__(256) void k_prep(
    const int* h_index, const int* r_index, const int* t_index,
    const float* hidden_states, const float* rel_embedding,
    const float* lin_W, const float* lin_b, const float* m1_W, const float* m1_b,
    const float* m2_W, const float* m2_b,
    int* hdr, float* cvec, float* hidden, float* score,
    unsigned* flag, int* tlist, unsigned* ctr){
  __shared__ int sh_fh[Bq], sh_ft[Bq], sh_r0[Bq], sh_hsrc, sh_tsrc;
  __shared__ float s_relv[Bq][Dd], s_cvec[Bq][Dd], s_hv[Dd], s_x[Bq][Dd], s_p[Bq][Dd];
  __shared__ float s_s0[Dd];
  __shared__ float sc0_sh;
  int tid = threadIdx.x;
  if (tid == 0){
    int n = 0;
    for (int b=0;b<Bq;b++){
      bool eq = true;
      for (int j=1;j<NEG;j++) eq = eq && (h_index[b*NEG+j]==h_index[b*NEG]);
      int h0 = eq ? h_index[b*NEG] : t_index[b*NEG];
      int t0 = eq ? t_index[b*NEG] : h_index[b*NEG];
      int r0 = eq ? r_index[b*NEG] : r_index[b*NEG] + NUM_REL;
      sh_fh[b] = h0 + b*Nn; sh_ft[b] = t0 + b*Nn; sh_r0[b] = r0;
      hdr[0+b] = sh_fh[b]; hdr[2+b] = sh_ft[b];
      for (int j=0;j<NEG;j++){
        int tj = eq ? t_index[b*NEG+j] : h_index[b*NEG+j];
        hdr[4 + b*NEG + j] = tj + b*Nn;
      }
      if (b==0){ sh_hsrc = h0; sh_tsrc = t0; }
      if (!flag[sh_ft[b]]){ flag[sh_ft[b]] = 1u; tlist[n++] = sh_ft[b]; }
      if (!flag[sh_fh[b]]){ flag[sh_fh[b]] = 1u; tlist[n++] = sh_fh[b]; }
    }
    ctr[3] = (unsigned)n;
  }
  __syncthreads();
  int b = tid >> 7, d = tid & 127;
  s_relv[b][d] = rel_embedding[(size_t)sh_r0[b]*Dd + d];
  if (b == 0){
    s_hv[d] = hidden_states[(size_t)sh_hsrc*Dd + d];
    s_s0[d] = fmaxf(m1_b[d], 0.f) * m2_W[d];   // untouched-node score terms
  }
  __syncthreads();
  if (tid == 0){
    float s = m2_b[0];
    for (int k=0;k<Dd;k++) s += s_s0[k];
    sc0_sh = s;
    ctr[4] = __float_as_uint(s);
  }
  // cvec[b] = rel @ lin_W[D:2D,:] + lin_b
  float acc = lin_b[d];
  for (int k=0;k<Dd;k++) acc += s_relv[b][k]*lin_W[(Dd+k)*Dd + d];
  s_cvec[b][d] = acc; cvec[b*Dd+d] = acc;
  // boundary scatter: t first, h second (h overrides; same thread => ordered)
  hidden[(size_t)sh_ft[b]*Dd + d] = hidden_states[(size_t)sh_tsrc*Dd + d];
  hidden[(size_t)sh_fh[b]*Dd + d] = hidden_states[(size_t)sh_hsrc*Dd + d];
  __syncthreads();
  // fill score with untouched constant
  float sc0 = sc0_sh;
  for (int i = tid; i < BN; i += 256) score[i] = sc0;
  // initial score at head nodes
  float hv = s_hv[d];
  float heur = s_cvec[b][d];
  for (int k=0;k<Dd;k++) heur += s_hv[k]*lin_W[k*Dd + d];
  s_x[b][d] = heur * hv;
  __syncthreads();
  float a2 = m1_b[d];
  for (int k=0;k<Dd;k++) a2 += s_x[b][k]*m1_W[k*Dd + d];
  s_p[b][d] = fmaxf(a2, 0.f) * m2_W[d];
  __syncthreads();
  if (tid < Bq){
    float s = m2_b[0];
    for (int k=0;k<Dd;k++) s += s_p[tid][k];
    score[sh_fh[tid]] = s;
  }
}

// Exact top-K radix select over touched keys (explicit, LDS) + untouched keys
// (analytic: all share score sc0, indices = complement of touched set).
__global__ __launch_bounds__(256) void k_select(
    const float* score, const int* tlist, const unsigned* ctr,
    unsigned long long* thr){
  int b = blockIdx.x;
  int nt = (int)ctr[3];
  unsigned d0 = ~encf(__uint_as_float(ctr[4]));   // top-32 of every untouched key
  __shared__ unsigned sd[SELCAP];
  __shared__ unsigned short sidx[SELCAP];
  __shared__ unsigned hist[256], histT[256];
  __shared__ int ntb_sh;
  __shared__ unsigned long long pref_sh;
  __shared__ unsigned kk_sh;
  int tid = threadIdx.x;
  if (tid==0){ ntb_sh = 0; pref_sh = 0ull; kk_sh = K_SEL; }
  __syncthreads();
  int vlo = b*Nn, vhi = vlo + Nn;
  for (int i = tid; i < nt; i += 256){
    int v = tlist[i];
    if (v >= vlo && v < vhi){
      int pos = atomicAdd(&ntb_sh, 1);
      if (pos < SELCAP){
        sd[pos] = ~encf(score[v]);
        sidx[pos] = (unsigned short)(v - vlo);
      }
    }
  }
  __syncthreads();
  int ntb = min(ntb_sh, SELCAP);
  unsigned nvirt = (unsigned)(Nn - ntb);
  for (int pass = 7; pass >= 0; --pass){
    hist[tid] = 0u; histT[tid] = 0u;
    __syncthreads();
    unsigned long long pref = pref_sh;
    int sh_hi = 8*(pass+1);
    // explicit (touched) keys
    for (int j = tid; j < ntb; j += 256){
      unsigned long long key = ((unsigned long long)sd[j] << 32) | (unsigned long long)sidx[j];
      bool ok = (pass==7) || ((key >> sh_hi) == (pref >> sh_hi));
      if (ok) atomicAdd(&hist[(unsigned)(key >> (8*pass)) & 255u], 1u);
      if (pass < 4){
        unsigned idx = sidx[j];
        bool oki = (pass == 3) || ((idx >> sh_hi) == (((unsigned)pref) >> sh_hi));
        if (oki) atomicAdd(&histT[(idx >> (8*pass)) & 255u], 1u);
      }
    }
    __syncthreads();
    // virtual (untouched) keys: score part = d0, index part = complement set
    if (pass >= 4){
      if (tid == 0){
        unsigned long long keyv_hi = ((unsigned long long)d0 << 32);
        bool ok = (pass==7) || ((keyv_hi >> sh_hi) == (pref >> sh_hi));
        if (ok) atomicAdd(&hist[(d0 >> (8*(pass-4))) & 255u], nvirt);
      }
    } else {
      if ((unsigned)(pref >> 32) == d0){
        unsigned long long hf = 0ull;
        if (pass < 3) hf = (unsigned long long)((((unsigned)pref) >> sh_hi)) << sh_hi;
        unsigned long long lo = hf + ((unsigned long long)tid << (8*pass));
        unsigned long long hi = lo + (1ull << (8*pass));
        unsigned long long nn = (unsigned long long)Nn;
        unsigned long long l2 = lo < nn ? lo : nn;
        unsigned long long h2 = hi < nn ? hi : nn;
        if (h2 > l2){
          unsigned c = (unsigned)(h2 - l2) - histT[tid];
          if (c > 0u) atomicAdd(&hist[tid], c);
        }
      }
    }
    __syncthreads();
    if (tid < 256){
      unsigned kk = kk_sh;
      unsigned cum = 0;
      for (int i=0;i<tid;i++) cum += hist[i];
      unsigned h = hist[tid];
      if (h > 0u && cum < kk && kk <= cum + h){
        pref_sh |= ((unsigned long long)tid) << (8*pass);
        kk_sh = kk - cum;
      }
    }
    __syncthreads();
  }
  if (tid==0) thr[b] = pref_sh;
}

// mask + all per-layer zeroing fused
__global__ void k_mask(const float* score, const unsigned long long* thr, unsigned* sel,
                       unsigned* out_deg, float* s1, float* s2,
                       unsigned* mxb, unsigned* mnb, unsigned* cnt, unsigned* ctr){
  int i = blockIdx.x*blockDim.x + threadIdx.x;
  if (i < BN){
    int b = i / Nn; int v = i - b*Nn;
    sel[i] = (make_key(score[i], v) <= thr[b]) ? 1u : 0u;
    out_deg[i] = 0u;
  }
  if (i < MAXACT*Dd){ s1[i]=0.f; s2[i]=0.f; mxb[i]=0u; mnb[i]=0xFFFFFFFFu; }
  if (i < MAXACT) cnt[i]=0u;
  if (i < 3) ctr[i]=0u;      // keep ctr[3] (touched), ctr[4] (sc0)
}

__global__ void k_degree(const int* ei, const unsigned* sel, unsigned* out_deg){
  int e = blockIdx.x*blockDim.x + threadIdx.x;
  if (e >= Ee) return;
  int s0 = ei[e];
  #pragma unroll
  for (int b=0;b<Bq;b++){
    int v = s0 + b*Nn;
    if (sel[v]) atomicAdd(&out_deg[v], 1u);
  }
}

__global__ void k_active(const unsigned* out_deg, int* node_slot, int* alist,
                         float* slot_deg, unsigned* ctr, unsigned* flag, int* tlist){
  int v = blockIdx.x*blockDim.x + threadIdx.x;
  if (v >= BN) return;
  unsigned dg = out_deg[v];
  if (dg > 0u){
    int slot = (int)atomicAdd(&ctr[0], 1u);
    alist[slot] = v; node_slot[v] = slot; slot_deg[slot] = (float)dg;
    atomicAdd((float*)&ctr[2], logf((float)dg + 1.0f));
    if (atomicExch(&flag[v], 1u) == 0u){
      int p = (int)atomicAdd(&ctr[3], 1u);
      tlist[p] = v;
    }
  }
}

__global__ void k_edges(const int* ei, const unsigned* sel, const unsigned* out_deg,
                        const int* node_slot, int* edges, unsigned* cnt, unsigned* ctr){
  int e = blockIdx.x*blockDim.x + threadIdx.x;
  if (e >= Ee) return;
  int s0 = ei[e], d0 = ei[Ee + e];
  #pragma unroll
  for (int b=0;b<Bq;b++){
    int s = s0 + b*Nn, dv = d0 + b*Nn;
    if (sel[s] && out_deg[dv] > 0u){
      int slot = node_slot[dv];
      int j = (int)atomicAdd(&ctr[1], 1u);
      edges[2*j] = s; edges[2*j+1] = slot;
      atomicAdd(&cnt[slot], 1u);
    }
  }
}

// 4 edges per block: amortize preW streaming
__global__ __launch_bounds__(128) void k_messages(
    const float* hidden, const int* edges, const int* alist,
    const float* preW, const float* preb,
    float* s1, float* s2, unsigned* mxb, unsigned* mnb, const unsigned* ctr){
  int ne = (int)ctr[1];
  int tid = threadIdx.x;
  __shared__ float sd[4][Dd], ss[4][Dd];
  __shared__ int dsl[4];
  float pb = preb[tid];
  for (int j0 = blockIdx.x*4; j0 < ne; j0 += gridDim.x*4){
    int nv = ne - j0; if (nv > 4) nv = 4;
    if (tid < 4){
      int j = j0 + ((tid < nv) ? tid : 0);
      dsl[tid] = edges[2*j+1];
    }
    #pragma unroll
    for (int e=0;e<4;e++){
      int j = j0 + ((e < nv) ? e : 0);
      int s = edges[2*j];
      int dv = alist[edges[2*j+1]];
      sd[e][tid] = hidden[(size_t)dv*Dd + tid];
      ss[e][tid] = hidden[(size_t)s*Dd + tid];
    }
    __syncthreads();
    float a[4] = {pb, pb, pb, pb};
    for (int k=0;k<Dd;k++){
      float w0 = preW[k*Dd + tid];
      float w1 = preW[(Dd+k)*Dd + tid];
      #pragma unroll
      for (int e=0;e<4;e++) a[e] += sd[e][k]*w0 + ss[e][k]*w1;
    }
    for (int e=0;e<nv;e++){
      int dslot = dsl[e];
      atomicAdd(&s1[dslot*Dd + tid], a[e]);
      atomicAdd(&s2[dslot*Dd + tid], a[e]*a[e]);
      atomicMax(&mxb[dslot*Dd + tid], encf(a[e]));
      atomicMin(&mnb[dslot*Dd + tid], encf(a[e]));
    }
    __syncthreads();
  }
}

// fused finalize+post GEMM: grid = 64 row-tiles x 4 k-chunks x 2 col-halves
__global__ __launch_bounds__(256) void k_post(
    const unsigned* cnt, const float* s1, const float* s2,
    const unsigned* mxb, const unsigned* mnb, const float* slot_deg,
    const float* postW, float* tpart, const unsigned* ctr){
  int na = (int)ctr[0];
  int bid = blockIdx.x;
  int tile = bid & 63, ch = (bid >> 6) & 3, half = bid >> 8;
  if (tile*32 >= na) return;
  float logsum = __uint_as_float(ctr[2]);
  float avg = (logsum + (float)(BN - na)*LN2F) / (float)BN;
  __shared__ float lb[32*Dd];
  __shared__ float sden[32];
  __shared__ unsigned shas[32];
  int tid = threadIdx.x;
  if (tid < 32){
    unsigned c = cnt[tile*32 + tid];
    sden[tid] = fmaxf((float)c, 1.0f);
    shas[tid] = c;
  }
  __syncthreads();
  for (int idx = tid; idx < 32*Dd; idx += 256){
    int sl = idx >> 7, kk = idx & 127;
    int gi = (tile*32 + sl)*Dd + kk;
    float den = sden[sl];
    float val;
    if (ch == 0)      val = s1[gi]/den;
    else if (ch == 1) val = shas[sl] ? decf(mxb[gi]) : 0.f;
    else if (ch == 2) val = shas[sl] ? decf(mnb[gi]) : 0.f;
    else {
      float mv = s1[gi]/den;
      float var = s2[gi]/den - mv*mv;
      val = sqrtf(fmaxf(var, 0.f) + EPSV);
    }
    lb[idx] = val;
  }
  __syncthreads();
  int cg = tid & 15, rg = tid >> 4;           // 64 cols (cg*4), 32 rows (rg*2)
  int ccol0 = half*64 + cg*4;
  float a0[2][4], a1[2][4], a2[2][4];
  #pragma unroll
  for (int i=0;i<2;i++)
    #pragma unroll
    for (int j=0;j<4;j++){ a0[i][j]=0.f; a1[i][j]=0.f; a2[i][j]=0.f; }
  for (int k4=0; k4<32; ++k4){
    float4 av[2];
    #pragma unroll
    for (int i=0;i<2;i++) av[i] = ((float4*)lb)[(rg*2+i)*32 + k4];
    #pragma unroll
    for (int j=0;j<4;j++){
      int krow = ch*128 + k4*4 + j;
      const float* wp = postW + (size_t)krow*Dd + ccol0;
      float4 w0 = *(const float4*)(wp);
      float4 w1 = *(const float4*)(wp + 512*Dd);
      float4 w2 = *(const float4*)(wp + 1024*Dd);
      #pragma unroll
      for (int i=0;i<2;i++){
        float a = (&av[i].x)[j];
        a0[i][0] += a*w0.x; a0[i][1] += a*w0.y; a0[i][2] += a*w0.z; a0[i][3] += a*w0.w;
        a1[i][0] += a*w1.x; a1[i][1] += a*w1.y; a1[i][2] += a*w1.z; a1[i][3] += a*w1.w;
        a2[i][0] += a*w2.x; a2[i][1] += a*w2.y; a2[i][2] += a*w2.z; a2[i][3] += a*w2.w;
      }
    }
  }
  #pragma unroll
  for (int i=0;i<2;i++){
    int slot = tile*32 + rg*2 + i;
    if (slot < na){
      float dg = slot_deg[slot];
      float logd = logf(dg + 1.f);
      float al = logd/avg, be = avg/logd;
      float4 r;
      r.x = a0[i][0] + al*a1[i][0] + be*a2[i][0];
      r.y = a0[i][1] + al*a1[i][1] + be*a2[i][1];
      r.z = a0[i][2] + al*a1[i][2] + be*a2[i][2];
      r.w = a0[i][3] + al*a1[i][3] + be*a2[i][3];
      *(float4*)(tpart + (size_t)ch*MAXACT*Dd + (size_t)slot*Dd + ccol0) = r;
    }
  }
}

__global__ __launch_bounds__(128) void k_out_resid(
    const float* tpart, const int* alist, const float* outW, const float* outb,
    const float* postb, float* hidden, const unsigned* ctr){
  int slot = blockIdx.x;
  if (slot >= (int)ctr[0]) return;
  int tid = threadIdx.x;
  __shared__ float tr[Dd];
  size_t o = (size_t)slot*Dd + tid;
  tr[tid] = tpart[o] + tpart[(size_t)MAXACT*Dd + o] + tpart[(size_t)2*MAXACT*Dd + o]
          + tpart[(size_t)3*MAXACT*Dd + o] + postb[tid];
  __syncthreads();
  int v = alist[slot];
  float acc = outb[tid];
  for (int k4=0;k4<32;k4++){
    float4 t4 = *(float4*)&tr[k4*4];
    acc += t4.x*outW[(k4*4+0)*Dd + tid];
    acc += t4.y*outW[(k4*4+1)*Dd + tid];
    acc += t4.z*outW[(k4*4+2)*Dd + tid];
    acc += t4.w*outW[(k4*4+3)*Dd + tid];
  }
  hidden[(size_t)v*Dd + tid] += acc;
}

// score only touched nodes; 32 rows/block, 4x4 register tile
__global__ __launch_bounds__(256) void k_score(
    const float* hidden, const float* cvec, const float* linW,
    const float* m1W, const float* m1b, const float* m2W, const float* m2b,
    const int* tlist, const unsigned* ctr, float* score){
  int nt = (int)ctr[3];
  int nb = blockIdx.x * 32;
  if (nb >= nt) return;
  __shared__ float sh[32*Dd];
  __shared__ float sx[32*Dd];
  __shared__ float sc[2*Dd];
  __shared__ int   sv[32];
  __shared__ float red[32*33];
  int tid = threadIdx.x;
  if (tid < 32){
    int idx = nb + tid;
    sv[tid] = (idx < nt) ? tlist[idx] : tlist[nb];
  }
  sc[tid] = cvec[tid];
  __syncthreads();
  for (int q = tid; q < 32*32; q += 256){
    int row = q >> 5, f4 = q & 31;
    ((float4*)sh)[row*32 + f4] = ((const float4*)(hidden + (size_t)sv[row]*Dd))[f4];
  }
  __syncthreads();
  int cg = tid & 31, rg = tid >> 5;  // cols cg*4, rows rg*4..+3
  int c0 = cg*4;
  float acc[4][4];
  #pragma unroll
  for (int i=0;i<4;i++){ acc[i][0]=0.f; acc[i][1]=0.f; acc[i][2]=0.f; acc[i][3]=0.f; }
  for (int k4=0;k4<32;k4++){
    float4 av[4];
    #pragma unroll
    for (int i=0;i<4;i++) av[i] = ((float4*)sh)[(rg*4+i)*32 + k4];
    #pragma unroll
    for (int j=0;j<4;j++){
      float4 w = *(const float4*)(linW + (size_t)(k4*4+j)*Dd + c0);
      #pragma unroll
      for (int i=0;i<4;i++){
        float a = (&av[i].x)[j];
        acc[i][0] += a*w.x; acc[i][1] += a*w.y; acc[i][2] += a*w.z; acc[i][3] += a*w.w;
      }
    }
  }
  #pragma unroll
  for (int i=0;i<4;i++){
    int row = rg*4 + i;
    int bb = (sv[row] >= Nn) ? 1 : 0;
    float4 cv = *(float4*)&sc[bb*Dd + c0];
    float4 hv = ((float4*)sh)[row*32 + cg];
    float4 x;
    x.x = (acc[i][0] + cv.x)*hv.x;
    x.y = (acc[i][1] + cv.y)*hv.y;
    x.z = (acc[i][2] + cv.z)*hv.z;
    x.w = (acc[i][3] + cv.w)*hv.w;
    ((float4*)sx)[row*32 + cg] = x;
  }
  __syncthreads();
  #pragma unroll
  for (int i=0;i<4;i++){ acc[i][0]=0.f; acc[i][1]=0.f; acc[i][2]=0.f; acc[i][3]=0.f; }
  for (int k4=0;k4<32;k4++){
    float4 av[4];
    #pragma unroll
    for (int i=0;i<4;i++) av[i] = ((float4*)sx)[(rg*4+i)*32 + k4];
    #pragma unroll
    for (int j=0;j<4;j++){
      float4 w = *(const float4*)(m1W + (size_t)(k4*4+j)*Dd + c0);
      #pragma unroll
      for (int i=0;i<4;i++){
        float a = (&av[i].x)[j];
        acc[i][0] += a*w.x; acc[i][1] += a*w.y; acc[i][2] += a*w.z; acc[i][3] += a*w.w;
      }
    }
  }
  float4 mb = *(const float4*)(m1b + c0);
  float4 mw = *(const float4*)(m2W + c0);
  #pragma unroll
  for (int i=0;i<4;i++){
    float p0 = fmaxf(acc[i][0]+mb.x, 0.f)*mw.x;
    float p1 = fmaxf(acc[i][1]+mb.y, 0.f)*mw.y;
    float p2 = fmaxf(acc[i][2]+mb.z, 0.f)*mw.z;
    float p3 = fmaxf(acc[i][3]+mb.w, 0.f)*mw.w;
    red[(rg*4+i)*33 + cg] = p0+p1+p2+p3;
  }
  __syncthreads();
  if (tid < 32){
    float s = m2b[0];
    for (int g=0; g<32; g++) s += red[tid*33 + g];
    if (nb + tid < nt) score[sv[tid]] = s;
  }
}

__global__ void k_gather(const float* score, const int* hdr, float* out){
  int i = threadIdx.x;
  if (i < Bq*NEG) out[i] = score[hdr[4+i]];
}

// ---------------- launch ----------------
extern "C" void kernel_launch(void* const* d_in, const int* in_sizes, int n_in,
                              void* d_out, int out_size, void* d_ws, size_t ws_size,
                              hipStream_t stream){
  const int*   h_index       = (const int*)d_in[0];
  const int*   r_index       = (const int*)d_in[1];
  const int*   t_index       = (const int*)d_in[2];
  const float* hidden_states = (const float*)d_in[3];
  const int*   edge_index    = (const int*)d_in[4];
  const float* rel_embedding = (const float*)d_in[5];
  const float* lin_W  = (const float*)d_in[6];
  const float* lin_b  = (const float*)d_in[7];
  const float* m1_W   = (const float*)d_in[8];
  const float* m1_b   = (const float*)d_in[9];
  const float* m2_W   = (const float*)d_in[10];
  const float* m2_b   = (const float*)d_in[11];
  const float* pre_W  = (const float*)d_in[12];
  const float* pre_b  = (const float*)d_in[13];
  const float* post_W = (const float*)d_in[14];
  const float* post_b = (const float*)d_in[15];
  const float* out_W  = (const float*)d_in[16];
  const float* out_b  = (const float*)d_in[17];

  char* ws = (char*)d_ws;
  float*    hidden   = (float*)(ws + HID_OFF);
  float*    score    = (float*)(ws + SCORE_OFF);
  float*    cvec     = (float*)(ws + CVEC_OFF);
  int*      hdr      = (int*)(ws + HDR_OFF);
  unsigned long long* thr = (unsigned long long*)(ws + THR_OFF);
  unsigned* sel      = (unsigned*)(ws + SEL_OFF);
  unsigned* out_deg  = (unsigned*)(ws + DEG_OFF);
  int*      node_slot= (int*)(ws + SLOT_OFF);
  unsigned* cnt      = (unsigned*)(ws + CNT_OFF);
  float*    slot_deg = (float*)(ws + SDEG_OFF);
  float*    s1       = (float*)(ws + S1_OFF);
  float*    s2       = (float*)(ws + S2_OFF);
  unsigned* mxb      = (unsigned*)(ws + MXB_OFF);
  unsigned* mnb      = (unsigned*)(ws + MNB_OFF);
  float*    tpart    = (float*)(ws + TPART_OFF);
  int*      alist    = (int*)(ws + ALIST_OFF);
  unsigned* flag     = (unsigned*)(ws + FLAG_OFF);
  int*      tlist    = (int*)(ws + TLIST_OFF);
  int*      edges    = (int*)(ws + EDGE_OFF);
  unsigned* ctr      = (unsigned*)(ws + CTR_OFF);

  k_zero<<<(BN*Dd/4 + 255)/256, 256, 0, stream>>>(hidden, flag);
  k_prep<<<1, 256, 0, stream>>>(h_index, r_index, t_index, hidden_states, rel_embedding,
                                lin_W, lin_b, m1_W, m1_b, m2_W, m2_b,
                                hdr, cvec, hidden, score, flag, tlist, ctr);
  for (int l = 0; l < Ll; ++l){
    const float* preWl  = pre_W  + (size_t)l*2*Dd*Dd;
    const float* prebl  = pre_b  + (size_t)l*Dd;
    const float* postWl = post_W + (size_t)l*12*Dd*Dd;
    const float* postbl = post_b + (size_t)l*Dd;
    const float* outWl  = out_W  + (size_t)l*Dd*Dd;
    const float* outbl  = out_b  + (size_t)l*Dd;

    k_select<<<Bq, 256, 0, stream>>>(score, tlist, ctr, thr);
    k_mask<<<(MAXACT*Dd + 255)/256, 256, 0, stream>>>(score, thr, sel, out_deg,
                                                      s1, s2, mxb, mnb, cnt, ctr);
    k_degree<<<(Ee + 255)/256, 256, 0, stream>>>(edge_index, sel, out_deg);
    k_active<<<(BN + 255)/256, 256, 0, stream>>>(out_deg, node_slot, alist, slot_deg,
                                                 ctr, flag, tlist);
    k_edges<<<(Ee + 255)/256, 256, 0, stream>>>(edge_index, sel, out_deg, node_slot,
                                                edges, cnt, ctr);
    k_messages<<<512, 128, 0, stream>>>(hidden, edges, alist, preWl, prebl,
                                        s1, s2, mxb, mnb, ctr);
    k_post<<<512, 256, 0, stream>>>(cnt, s1, s2, mxb, mnb, slot_deg, postWl, tpart, ctr);
    k_out_resid<<<MAXACT, 128, 0, stream>>>(tpart, alist, outWl, outbl, postbl, hidden, ctr);
    k_score<<<MAXTOUCH/32, 256, 0, stream>>>(hidden, cvec, lin_W, m1_W, m1_b, m2_W, m2_b,
                                             tlist, ctr, score);
  }
  k_gather<<<1, 64, 0, stream>>>(score, hdr, (float*)d_out);
}

// Round 4
// 481.739 us; speedup vs baseline: 1.6971x; 1.0679x over previous
//
#include <hip/hip_runtime.h>
#include <math.h>

#define Bq 2
#define NEG 16
#define Nn 10000
#define Ee 80000
#define Dd 128
#define NUM_REL 237
#define Ll 3
#define K_SEL 1000
#define BN (Bq*Nn)
#define EPSV 1e-5f
#define MAXACT 2048
#define MAXTOUCH 8192
#define SELCAP 3328
#define LN2F 0.69314718056f

// ---------------- workspace layout (bytes) ----------------
constexpr size_t HID_OFF   = 0;                                   // BN*D f32
constexpr size_t SCORE_OFF = HID_OFF   + (size_t)BN*Dd*4;         // BN f32
constexpr size_t CVEC_OFF  = SCORE_OFF + (size_t)BN*4;            // B*D f32
constexpr size_t HDR_OFF   = CVEC_OFF  + (size_t)Bq*Dd*4;         // 64 i32
constexpr size_t THR_OFF   = HDR_OFF   + 64*4;                    // B u64
constexpr size_t SEL_OFF   = THR_OFF   + Bq*8;                    // BN u32
constexpr size_t DEG_OFF   = SEL_OFF   + (size_t)BN*4;            // BN u32
constexpr size_t SLOT_OFF  = DEG_OFF   + (size_t)BN*4;            // BN i32
constexpr size_t CNT_OFF   = SLOT_OFF  + (size_t)BN*4;            // MAXACT u32
constexpr size_t SDEG_OFF  = CNT_OFF   + (size_t)MAXACT*4;        // MAXACT f32
constexpr size_t S1_OFF    = SDEG_OFF  + (size_t)MAXACT*4;        // MAXACT*D f32
constexpr size_t S2_OFF    = S1_OFF    + (size_t)MAXACT*Dd*4;
constexpr size_t MXB_OFF   = S2_OFF    + (size_t)MAXACT*Dd*4;     // MAXACT*D u32
constexpr size_t MNB_OFF   = MXB_OFF   + (size_t)MAXACT*Dd*4;
constexpr size_t TPART_OFF = MNB_OFF   + (size_t)MAXACT*Dd*4;     // 4*MAXACT*D f32
constexpr size_t ALIST_OFF = TPART_OFF + (size_t)4*MAXACT*Dd*4;   // MAXACT i32
constexpr size_t FLAG_OFF  = ALIST_OFF + (size_t)MAXACT*4;        // BN u32
constexpr size_t TLIST_OFF = FLAG_OFF  + (size_t)BN*4;            // MAXTOUCH i32
constexpr size_t EDGE_OFF  = TLIST_OFF + (size_t)MAXTOUCH*4;      // B*E*2 i32
constexpr size_t CTR_OFF   = EDGE_OFF  + (size_t)Bq*Ee*2*4;       // 16 u32
// ctr[0]=na ctr[1]=ne ctr[2]=sum(log(deg+1)) f32-bits ctr[3]=ntouched ctr[4]=sc0 f32-bits

// ---------------- helpers ----------------
__device__ __forceinline__ unsigned encf(float f){
  unsigned u = __float_as_uint(f);
  return (u & 0x80000000u) ? ~u : (u | 0x80000000u);
}
__device__ __forceinline__ float decf(unsigned e){
  unsigned u = (e & 0x80000000u) ? (e & 0x7FFFFFFFu) : ~e;
  return __uint_as_float(u);
}
__device__ __forceinline__ unsigned long long make_key(float f, int i){
  unsigned d = ~encf(f);
  return ((unsigned long long)d << 32) | (unsigned)i;
}

// ---------------- kernels ----------------
__global__ void k_zero(float* hidden, unsigned* flag){
  int i = blockIdx.x*blockDim.x + threadIdx.x;
  if (i < BN*Dd/4) ((float4*)hidden)[i] = make_float4(0.f,0.f,0.f,0.f);
  if (i < BN) flag[i] = 0u;
}

__global__ __launch_bounds__(256) void k_prep(
    const int* h_index, const int* r_index, const int* t_index,
    const float* hidden_states, const float* rel_embedding,
    const float* lin_W, const float* lin_b, const float* m1_W, const float* m1_b,
    const float* m2_W, const float* m2_b,
    int* hdr, float* cvec, float* hidden, float* score,
    unsigned* flag, int* tlist, unsigned* ctr){
  __shared__ int sh_fh[Bq], sh_ft[Bq], sh_r0[Bq], sh_hsrc, sh_tsrc;
  __shared__ float s_relv[Bq][Dd], s_cvec[Bq][Dd], s_hv[Dd], s_x[Bq][Dd], s_p[Bq][Dd];
  __shared__ float s_s0[Dd];
  __shared__ float sc0_sh;
  int tid = threadIdx.x;
  if (tid == 0){
    int n = 0;
    for (int b=0;b<Bq;b++){
      bool eq = true;
      for (int j=1;j<NEG;j++) eq = eq && (h_index[b*NEG+j]==h_index[b*NEG]);
      int h0 = eq ? h_index[b*NEG] : t_index[b*NEG];
      int t0 = eq ? t_index[b*NEG] : h_index[b*NEG];
      int r0 = eq ? r_index[b*NEG] : r_index[b*NEG] + NUM_REL;
      sh_fh[b] = h0 + b*Nn; sh_ft[b] = t0 + b*Nn; sh_r0[b] = r0;
      hdr[0+b] = sh_fh[b]; hdr[2+b] = sh_ft[b];
      for (int j=0;j<NEG;j++){
        int tj = eq ? t_index[b*NEG+j] : h_index[b*NEG+j];
        hdr[4 + b*NEG + j] = tj + b*Nn;
      }
      if (b==0){ sh_hsrc = h0; sh_tsrc = t0; }
      if (!flag[sh_ft[b]]){ flag[sh_ft[b]] = 1u; tlist[n++] = sh_ft[b]; }
      if (!flag[sh_fh[b]]){ flag[sh_fh[b]] = 1u; tlist[n++] = sh_fh[b]; }
    }
    ctr[3] = (unsigned)n;
  }
  __syncthreads();
  int b = tid >> 7, d = tid & 127;
  s_relv[b][d] = rel_embedding[(size_t)sh_r0[b]*Dd + d];
  if (b == 0){
    s_hv[d] = hidden_states[(size_t)sh_hsrc*Dd + d];
    s_s0[d] = fmaxf(m1_b[d], 0.f) * m2_W[d];   // untouched-node score terms
  }
  __syncthreads();
  if (tid == 0){
    float s = m2_b[0];
    for (int k=0;k<Dd;k++) s += s_s0[k];
    sc0_sh = s;
    ctr[4] = __float_as_uint(s);
  }
  // cvec[b] = rel @ lin_W[D:2D,:] + lin_b
  float acc = lin_b[d];
  #pragma unroll 8
  for (int k=0;k<Dd;k++) acc += s_relv[b][k]*lin_W[(Dd+k)*Dd + d];
  s_cvec[b][d] = acc; cvec[b*Dd+d] = acc;
  // boundary scatter: t first, h second (h overrides; same thread => ordered)
  hidden[(size_t)sh_ft[b]*Dd + d] = hidden_states[(size_t)sh_tsrc*Dd + d];
  hidden[(size_t)sh_fh[b]*Dd + d] = hidden_states[(size_t)sh_hsrc*Dd + d];
  __syncthreads();
  // fill score with untouched constant
  float sc0 = sc0_sh;
  for (int i = tid; i < BN; i += 256) score[i] = sc0;
  // initial score at head nodes
  float hv = s_hv[d];
  float heur = s_cvec[b][d];
  #pragma unroll 8
  for (int k=0;k<Dd;k++) heur += s_hv[k]*lin_W[k*Dd + d];
  s_x[b][d] = heur * hv;
  __syncthreads();
  float a2 = m1_b[d];
  #pragma unroll 8
  for (int k=0;k<Dd;k++) a2 += s_x[b][k]*m1_W[k*Dd + d];
  s_p[b][d] = fmaxf(a2, 0.f) * m2_W[d];
  __syncthreads();
  if (tid < Bq){
    float s = m2_b[0];
    for (int k=0;k<Dd;k++) s += s_p[tid][k];
    score[sh_fh[tid]] = s;
  }
}

// Exact top-K radix select over touched keys (explicit, LDS) + untouched keys
// (analytic: all share score sc0, indices = complement of touched set).
__global__ __launch_bounds__(256) void k_select(
    const float* score, const int* tlist, const unsigned* ctr,
    unsigned long long* thr){
  int b = blockIdx.x;
  int nt = (int)ctr[3];
  unsigned d0 = ~encf(__uint_as_float(ctr[4]));   // top-32 of every untouched key
  __shared__ unsigned sd[SELCAP];
  __shared__ unsigned short sidx[SELCAP];
  __shared__ unsigned hist[256], histT[256];
  __shared__ int ntb_sh;
  __shared__ unsigned long long pref_sh;
  __shared__ unsigned kk_sh;
  int tid = threadIdx.x;
  if (tid==0){ ntb_sh = 0; pref_sh = 0ull; kk_sh = K_SEL; }
  __syncthreads();
  int vlo = b*Nn, vhi = vlo + Nn;
  for (int i = tid; i < nt; i += 256){
    int v = tlist[i];
    if (v >= vlo && v < vhi){
      int pos = atomicAdd(&ntb_sh, 1);
      if (pos < SELCAP){
        sd[pos] = ~encf(score[v]);
        sidx[pos] = (unsigned short)(v - vlo);
      }
    }
  }
  __syncthreads();
  int ntb = min(ntb_sh, SELCAP);
  unsigned nvirt = (unsigned)(Nn - ntb);
  for (int pass = 7; pass >= 0; --pass){
    hist[tid] = 0u; histT[tid] = 0u;
    __syncthreads();
    unsigned long long pref = pref_sh;
    int sh_hi = 8*(pass+1);
    // explicit (touched) keys
    for (int j = tid; j < ntb; j += 256){
      unsigned long long key = ((unsigned long long)sd[j] << 32) | (unsigned long long)sidx[j];
      bool ok = (pass==7) || ((key >> sh_hi) == (pref >> sh_hi));
      if (ok) atomicAdd(&hist[(unsigned)(key >> (8*pass)) & 255u], 1u);
      if (pass < 4){
        unsigned idx = sidx[j];
        bool oki = (pass == 3) || ((idx >> sh_hi) == (((unsigned)pref) >> sh_hi));
        if (oki) atomicAdd(&histT[(idx >> (8*pass)) & 255u], 1u);
      }
    }
    __syncthreads();
    // virtual (untouched) keys: score part = d0, index part = complement set
    if (pass >= 4){
      if (tid == 0){
        unsigned long long keyv_hi = ((unsigned long long)d0 << 32);
        bool ok = (pass==7) || ((keyv_hi >> sh_hi) == (pref >> sh_hi));
        if (ok) atomicAdd(&hist[(d0 >> (8*(pass-4))) & 255u], nvirt);
      }
    } else {
      if ((unsigned)(pref >> 32) == d0){
        unsigned long long hf = 0ull;
        if (pass < 3) hf = (unsigned long long)((((unsigned)pref) >> sh_hi)) << sh_hi;
        unsigned long long lo = hf + ((unsigned long long)tid << (8*pass));
        unsigned long long hi = lo + (1ull << (8*pass));
        unsigned long long nn = (unsigned long long)Nn;
        unsigned long long l2 = lo < nn ? lo : nn;
        unsigned long long h2 = hi < nn ? hi : nn;
        if (h2 > l2){
          unsigned c = (unsigned)(h2 - l2) - histT[tid];
          if (c > 0u) atomicAdd(&hist[tid], c);
        }
      }
    }
    __syncthreads();
    if (tid < 256){
      unsigned kk = kk_sh;
      unsigned cum = 0;
      for (int i=0;i<tid;i++) cum += hist[i];
      unsigned h = hist[tid];
      if (h > 0u && cum < kk && kk <= cum + h){
        pref_sh |= ((unsigned long long)tid) << (8*pass);
        kk_sh = kk - cum;
      }
    }
    __syncthreads();
  }
  if (tid==0) thr[b] = pref_sh;
}

// mask + all per-layer zeroing fused
__global__ void k_mask(const float* score, const unsigned long long* thr, unsigned* sel,
                       unsigned* out_deg, float* s1, float* s2,
                       unsigned* mxb, unsigned* mnb, unsigned* cnt, unsigned* ctr){
  int i = blockIdx.x*blockDim.x + threadIdx.x;
  if (i < BN){
    int b = i / Nn; int v = i - b*Nn;
    sel[i] = (make_key(score[i], v) <= thr[b]) ? 1u : 0u;
    out_deg[i] = 0u;
  }
  if (i < MAXACT*Dd){ s1[i]=0.f; s2[i]=0.f; mxb[i]=0u; mnb[i]=0xFFFFFFFFu; }
  if (i < MAXACT) cnt[i]=0u;
  if (i < 3) ctr[i]=0u;      // keep ctr[3] (touched), ctr[4] (sc0)
}

__global__ void k_degree(const int* ei, const unsigned* sel, unsigned* out_deg){
  int e = blockIdx.x*blockDim.x + threadIdx.x;
  if (e >= Ee) return;
  int s0 = ei[e];
  #pragma unroll
  for (int b=0;b<Bq;b++){
    int v = s0 + b*Nn;
    if (sel[v]) atomicAdd(&out_deg[v], 1u);
  }
}

__global__ void k_active(const unsigned* out_deg, int* node_slot, int* alist,
                         float* slot_deg, unsigned* ctr, unsigned* flag, int* tlist){
  int v = blockIdx.x*blockDim.x + threadIdx.x;
  if (v >= BN) return;
  unsigned dg = out_deg[v];
  if (dg > 0u){
    int slot = (int)atomicAdd(&ctr[0], 1u);
    alist[slot] = v; node_slot[v] = slot; slot_deg[slot] = (float)dg;
    atomicAdd((float*)&ctr[2], logf((float)dg + 1.0f));
    if (atomicExch(&flag[v], 1u) == 0u){
      int p = (int)atomicAdd(&ctr[3], 1u);
      tlist[p] = v;
    }
  }
}

__global__ void k_edges(const int* ei, const unsigned* sel, const unsigned* out_deg,
                        const int* node_slot, int* edges, unsigned* cnt, unsigned* ctr){
  int e = blockIdx.x*blockDim.x + threadIdx.x;
  if (e >= Ee) return;
  int s0 = ei[e], d0 = ei[Ee + e];
  #pragma unroll
  for (int b=0;b<Bq;b++){
    int s = s0 + b*Nn, dv = d0 + b*Nn;
    if (sel[s] && out_deg[dv] > 0u){
      int slot = node_slot[dv];
      int j = (int)atomicAdd(&ctr[1], 1u);
      edges[2*j] = s; edges[2*j+1] = slot;
      atomicAdd(&cnt[slot], 1u);
    }
  }
}

// 4 edges per block: amortize preW streaming
__global__ __launch_bounds__(128) void k_messages(
    const float* hidden, const int* edges, const int* alist,
    const float* preW, const float* preb,
    float* s1, float* s2, unsigned* mxb, unsigned* mnb, const unsigned* ctr){
  int ne = (int)ctr[1];
  int tid = threadIdx.x;
  __shared__ float sd[4][Dd], ss[4][Dd];
  __shared__ int dsl[4];
  float pb = preb[tid];
  for (int j0 = blockIdx.x*4; j0 < ne; j0 += gridDim.x*4){
    int nv = ne - j0; if (nv > 4) nv = 4;
    if (tid < 4){
      int j = j0 + ((tid < nv) ? tid : 0);
      dsl[tid] = edges[2*j+1];
    }
    #pragma unroll
    for (int e=0;e<4;e++){
      int j = j0 + ((e < nv) ? e : 0);
      int s = edges[2*j];
      int dv = alist[edges[2*j+1]];
      sd[e][tid] = hidden[(size_t)dv*Dd + tid];
      ss[e][tid] = hidden[(size_t)s*Dd + tid];
    }
    __syncthreads();
    float a[4] = {pb, pb, pb, pb};
    #pragma unroll 4
    for (int k=0;k<Dd;k++){
      float w0 = preW[k*Dd + tid];
      float w1 = preW[(Dd+k)*Dd + tid];
      #pragma unroll
      for (int e=0;e<4;e++) a[e] += sd[e][k]*w0 + ss[e][k]*w1;
    }
    for (int e=0;e<nv;e++){
      int dslot = dsl[e];
      atomicAdd(&s1[dslot*Dd + tid], a[e]);
      atomicAdd(&s2[dslot*Dd + tid], a[e]*a[e]);
      atomicMax(&mxb[dslot*Dd + tid], encf(a[e]));
      atomicMin(&mnb[dslot*Dd + tid], encf(a[e]));
    }
    __syncthreads();
  }
}

// fused finalize+post GEMM, LDS-staged weights.
// grid = 64 row-tiles x 4 agg-chunks; 512 threads; K order identical to v2.
__global__ __launch_bounds__(512) void k_post(
    const unsigned* cnt, const float* s1, const float* s2,
    const unsigned* mxb, const unsigned* mnb, const float* slot_deg,
    const float* postW, float* tpart, const unsigned* ctr){
  int na = (int)ctr[0];
  int bid = blockIdx.x;
  int tile = bid & 63, ch = bid >> 6;
  if (tile*32 >= na) return;
  float logsum = __uint_as_float(ctr[2]);
  float avg = (logsum + (float)(BN - na)*LN2F) / (float)BN;
  __shared__ float lb[32*136];             // padded rows: 16B-aligned, conflict-free
  __shared__ float wbuf[3*16*128];         // Kc=16 chunk of W0/W1/W2
  __shared__ float sden[32];
  __shared__ unsigned shas[32];
  int tid = threadIdx.x;
  if (tid < 32){
    unsigned c = cnt[tile*32 + tid];
    sden[tid] = fmaxf((float)c, 1.0f);
    shas[tid] = c;
  }
  __syncthreads();
  for (int idx = tid; idx < 32*Dd; idx += 512){
    int sl = idx >> 7, kk = idx & 127;
    int gi = (tile*32 + sl)*Dd + kk;
    float den = sden[sl];
    float val;
    if (ch == 0)      val = s1[gi]/den;
    else if (ch == 1) val = shas[sl] ? decf(mxb[gi]) : 0.f;
    else if (ch == 2) val = shas[sl] ? decf(mnb[gi]) : 0.f;
    else {
      float mv = s1[gi]/den;
      float var = s2[gi]/den - mv*mv;
      val = sqrtf(fmaxf(var, 0.f) + EPSV);
    }
    lb[sl*136 + kk] = val;
  }
  int cg = tid & 31, rg = tid >> 5;        // 32 col-groups x 16 row-groups (2 rows)
  int c0 = cg*4;
  float a0[2][4], a1[2][4], a2[2][4];
  #pragma unroll
  for (int i=0;i<2;i++)
    #pragma unroll
    for (int j=0;j<4;j++){ a0[i][j]=0.f; a1[i][j]=0.f; a2[i][j]=0.f; }
  for (int chunk = 0; chunk < 8; ++chunk){
    // cooperative stage: rows [ch*128+chunk*16, +16) of W0,W1,W2
    #pragma unroll
    for (int i = 0; i < 3; ++i){
      int f = tid + i*512;                 // 1536 float4
      int q = f >> 9, r = f & 511;
      int kk = r >> 5, c4 = r & 31;
      int grow = q*512 + ch*128 + chunk*16 + kk;
      ((float4*)wbuf)[f] = *(const float4*)(postW + (size_t)grow*Dd + c4*4);
    }
    __syncthreads();
    #pragma unroll
    for (int k4 = 0; k4 < 4; ++k4){
      float4 av0 = *(const float4*)&lb[(rg*2+0)*136 + chunk*16 + k4*4];
      float4 av1 = *(const float4*)&lb[(rg*2+1)*136 + chunk*16 + k4*4];
      #pragma unroll
      for (int j = 0; j < 4; ++j){
        int kk = k4*4 + j;
        float4 w0 = *(const float4*)&wbuf[kk*128 + c0];
        float4 w1 = *(const float4*)&wbuf[(16+kk)*128 + c0];
        float4 w2 = *(const float4*)&wbuf[(32+kk)*128 + c0];
        float av[2] = { (&av0.x)[j], (&av1.x)[j] };
        #pragma unroll
        for (int i=0;i<2;i++){
          float a = av[i];
          a0[i][0] += a*w0.x; a0[i][1] += a*w0.y; a0[i][2] += a*w0.z; a0[i][3] += a*w0.w;
          a1[i][0] += a*w1.x; a1[i][1] += a*w1.y; a1[i][2] += a*w1.z; a1[i][3] += a*w1.w;
          a2[i][0] += a*w2.x; a2[i][1] += a*w2.y; a2[i][2] += a*w2.z; a2[i][3] += a*w2.w;
        }
      }
    }
    __syncthreads();
  }
  #pragma unroll
  for (int i=0;i<2;i++){
    int slot = tile*32 + rg*2 + i;
    if (slot < na){
      float dg = slot_deg[slot];
      float logd = logf(dg + 1.f);
      float al = logd/avg, be = avg/logd;
      float4 r;
      r.x = a0[i][0] + al*a1[i][0] + be*a2[i][0];
      r.y = a0[i][1] + al*a1[i][1] + be*a2[i][1];
      r.z = a0[i][2] + al*a1[i][2] + be*a2[i][2];
      r.w = a0[i][3] + al*a1[i][3] + be*a2[i][3];
      *(float4*)(tpart + (size_t)ch*MAXACT*Dd + (size_t)slot*Dd + c0) = r;
    }
  }
}

// 32 slots/block, LDS-staged outW; K order identical to v2 (outb first).
__global__ __launch_bounds__(256) void k_out_resid(
    const float* tpart, const int* alist, const float* outW, const float* outb,
    const float* postb, float* hidden, const unsigned* ctr){
  int na = (int)ctr[0];
  int tile = blockIdx.x;
  if (tile*32 >= na) return;
  __shared__ float tr[32*136];
  __shared__ float wbuf[16*128];
  int tid = threadIdx.x;
  for (int idx = tid; idx < 32*Dd; idx += 256){
    int sl = idx >> 7, kk = idx & 127;
    size_t o = (size_t)(tile*32 + sl)*Dd + kk;
    tr[sl*136 + kk] = tpart[o] + tpart[(size_t)MAXACT*Dd + o]
                    + tpart[(size_t)2*MAXACT*Dd + o] + tpart[(size_t)3*MAXACT*Dd + o]
                    + postb[kk];
  }
  int cg = tid & 31, rg = tid >> 5;        // 32 col-groups x 8 row-groups (4 rows)
  int c0 = cg*4;
  float4 ob = *(const float4*)(outb + c0);
  float acc[4][4];
  #pragma unroll
  for (int r=0;r<4;r++){ acc[r][0]=ob.x; acc[r][1]=ob.y; acc[r][2]=ob.z; acc[r][3]=ob.w; }
  for (int chunk = 0; chunk < 8; ++chunk){
    #pragma unroll
    for (int i = 0; i < 2; ++i){
      int f = tid + i*256;                 // 512 float4
      int kk = f >> 5, c4 = f & 31;
      ((float4*)wbuf)[f] = *(const float4*)(outW + (size_t)(chunk*16 + kk)*Dd + c4*4);
    }
    __syncthreads();
    #pragma unroll
    for (int k4 = 0; k4 < 4; ++k4){
      float4 av[4];
      #pragma unroll
      for (int r=0;r<4;r++)
        av[r] = *(const float4*)&tr[(rg*4+r)*136 + chunk*16 + k4*4];
      #pragma unroll
      for (int j = 0; j < 4; ++j){
        float4 w = *(const float4*)&wbuf[(k4*4+j)*128 + c0];
        #pragma unroll
        for (int r=0;r<4;r++){
          float a = (&av[r].x)[j];
          acc[r][0] += a*w.x; acc[r][1] += a*w.y; acc[r][2] += a*w.z; acc[r][3] += a*w.w;
        }
      }
    }
    __syncthreads();
  }
  #pragma unroll
  for (int r=0;r<4;r++){
    int slot = tile*32 + rg*4 + r;
    if (slot < na){
      int v = alist[slot];
      float* hp = hidden + (size_t)v*Dd + c0;
      float4 h4 = *(float4*)hp;
      h4.x += acc[r][0]; h4.y += acc[r][1]; h4.z += acc[r][2]; h4.w += acc[r][3];
      *(float4*)hp = h4;
    }
  }
}

// score rows from a list; normal layers use tlist/ctr, last layer uses hdr+4 (32 rows)
__global__ __launch_bounds__(256) void k_score(
    const float* hidden, const float* cvec, const float* linW,
    const float* m1W, const float* m1b, const float* m2W, const float* m2b,
    const int* tlist, const unsigned* ctr, float* score,
    const int* ovr, int ovr_n){
  int nt = (ovr_n > 0) ? ovr_n : (int)ctr[3];
  const int* list = (ovr_n > 0) ? ovr : tlist;
  int nb = blockIdx.x * 32;
  if (nb >= nt) return;
  __shared__ float sh[32*Dd];
  __shared__ float sx[32*Dd];
  __shared__ float sc[2*Dd];
  __shared__ int   sv[32];
  __shared__ float red[32*33];
  int tid = threadIdx.x;
  if (tid < 32){
    int idx = nb + tid;
    sv[tid] = (idx < nt) ? list[idx] : list[nb];
  }
  sc[tid] = cvec[tid];
  __syncthreads();
  for (int q = tid; q < 32*32; q += 256){
    int row = q >> 5, f4 = q & 31;
    ((float4*)sh)[row*32 + f4] = ((const float4*)(hidden + (size_t)sv[row]*Dd))[f4];
  }
  __syncthreads();
  int cg = tid & 31, rg = tid >> 5;  // cols cg*4, rows rg*4..+3
  int c0 = cg*4;
  float acc[4][4];
  #pragma unroll
  for (int i=0;i<4;i++){ acc[i][0]=0.f; acc[i][1]=0.f; acc[i][2]=0.f; acc[i][3]=0.f; }
  for (int k4=0;k4<32;k4++){
    float4 av[4];
    #pragma unroll
    for (int i=0;i<4;i++) av[i] = ((float4*)sh)[(rg*4+i)*32 + k4];
    #pragma unroll
    for (int j=0;j<4;j++){
      float4 w = *(const float4*)(linW + (size_t)(k4*4+j)*Dd + c0);
      #pragma unroll
      for (int i=0;i<4;i++){
        float a = (&av[i].x)[j];
        acc[i][0] += a*w.x; acc[i][1] += a*w.y; acc[i][2] += a*w.z; acc[i][3] += a*w.w;
      }
    }
  }
  #pragma unroll
  for (int i=0;i<4;i++){
    int row = rg*4 + i;
    int bb = (sv[row] >= Nn) ? 1 : 0;
    float4 cv = *(float4*)&sc[bb*Dd + c0];
    float4 hv = ((float4*)sh)[row*32 + cg];
    float4 x;
    x.x = (acc[i][0] + cv.x)*hv.x;
    x.y = (acc[i][1] + cv.y)*hv.y;
    x.z = (acc[i][2] + cv.z)*hv.z;
    x.w = (acc[i][3] + cv.w)*hv.w;
    ((float4*)sx)[row*32 + cg] = x;
  }
  __syncthreads();
  #pragma unroll
  for (int i=0;i<4;i++){ acc[i][0]=0.f; acc[i][1]=0.f; acc[i][2]=0.f; acc[i][3]=0.f; }
  for (int k4=0;k4<32;k4++){
    float4 av[4];
    #pragma unroll
    for (int i=0;i<4;i++) av[i] = ((float4*)sx)[(rg*4+i)*32 + k4];
    #pragma unroll
    for (int j=0;j<4;j++){
      float4 w = *(const float4*)(m1W + (size_t)(k4*4+j)*Dd + c0);
      #pragma unroll
      for (int i=0;i<4;i++){
        float a = (&av[i].x)[j];
        acc[i][0] += a*w.x; acc[i][1] += a*w.y; acc[i][2] += a*w.z; acc[i][3] += a*w.w;
      }
    }
  }
  float4 mb = *(const float4*)(m1b + c0);
  float4 mw = *(const float4*)(m2W + c0);
  #pragma unroll
  for (int i=0;i<4;i++){
    float p0 = fmaxf(acc[i][0]+mb.x, 0.f)*mw.x;
    float p1 = fmaxf(acc[i][1]+mb.y, 0.f)*mw.y;
    float p2 = fmaxf(acc[i][2]+mb.z, 0.f)*mw.z;
    float p3 = fmaxf(acc[i][3]+mb.w, 0.f)*mw.w;
    red[(rg*4+i)*33 + cg] = p0+p1+p2+p3;
  }
  __syncthreads();
  if (tid < 32){
    float s = m2b[0];
    for (int g=0; g<32; g++) s += red[tid*33 + g];
    if (nb + tid < nt) score[sv[tid]] = s;
  }
}

__global__ void k_gather(const float* score, const int* hdr, float* out){
  int i = threadIdx.x;
  if (i < Bq*NEG) out[i] = score[hdr[4+i]];
}

// ---------------- launch ----------------
extern "C" void kernel_launch(void* const* d_in, const int* in_sizes, int n_in,
                              void* d_out, int out_size, void* d_ws, size_t ws_size,
                              hipStream_t stream){
  const int*   h_index       = (const int*)d_in[0];
  const int*   r_index       = (const int*)d_in[1];
  const int*   t_index       = (const int*)d_in[2];
  const float* hidden_states = (const float*)d_in[3];
  const int*   edge_index    = (const int*)d_in[4];
  const float* rel_embedding = (const float*)d_in[5];
  const float* lin_W  = (const float*)d_in[6];
  const float* lin_b  = (const float*)d_in[7];
  const float* m1_W   = (const float*)d_in[8];
  const float* m1_b   = (const float*)d_in[9];
  const float* m2_W   = (const float*)d_in[10];
  const float* m2_b   = (const float*)d_in[11];
  const float* pre_W  = (const float*)d_in[12];
  const float* pre_b  = (const float*)d_in[13];
  const float* post_W = (const float*)d_in[14];
  const float* post_b = (const float*)d_in[15];
  const float* out_W  = (const float*)d_in[16];
  const float* out_b  = (const float*)d_in[17];

  char* ws = (char*)d_ws;
  float*    hidden   = (float*)(ws + HID_OFF);
  float*    score    = (float*)(ws + SCORE_OFF);
  float*    cvec     = (float*)(ws + CVEC_OFF);
  int*      hdr      = (int*)(ws + HDR_OFF);
  unsigned long long* thr = (unsigned long long*)(ws + THR_OFF);
  unsigned* sel      = (unsigned*)(ws + SEL_OFF);
  unsigned* out_deg  = (unsigned*)(ws + DEG_OFF);
  int*      node_slot= (int*)(ws + SLOT_OFF);
  unsigned* cnt      = (unsigned*)(ws + CNT_OFF);
  float*    slot_deg = (float*)(ws + SDEG_OFF);
  float*    s1       = (float*)(ws + S1_OFF);
  float*    s2       = (float*)(ws + S2_OFF);
  unsigned* mxb      = (unsigned*)(ws + MXB_OFF);
  unsigned* mnb      = (unsigned*)(ws + MNB_OFF);
  float*    tpart    = (float*)(ws + TPART_OFF);
  int*      alist    = (int*)(ws + ALIST_OFF);
  unsigned* flag     = (unsigned*)(ws + FLAG_OFF);
  int*      tlist    = (int*)(ws + TLIST_OFF);
  int*      edges    = (int*)(ws + EDGE_OFF);
  unsigned* ctr      = (unsigned*)(ws + CTR_OFF);

  k_zero<<<(BN*Dd/4 + 255)/256, 256, 0, stream>>>(hidden, flag);
  k_prep<<<1, 256, 0, stream>>>(h_index, r_index, t_index, hidden_states, rel_embedding,
                                lin_W, lin_b, m1_W, m1_b, m2_W, m2_b,
                                hdr, cvec, hidden, score, flag, tlist, ctr);
  for (int l = 0; l < Ll; ++l){
    const float* preWl  = pre_W  + (size_t)l*2*Dd*Dd;
    const float* prebl  = pre_b  + (size_t)l*Dd;
    const float* postWl = post_W + (size_t)l*12*Dd*Dd;
    const float* postbl = post_b + (size_t)l*Dd;
    const float* outWl  = out_W  + (size_t)l*Dd*Dd;
    const float* outbl  = out_b  + (size_t)l*Dd;

    k_select<<<Bq, 256, 0, stream>>>(score, tlist, ctr, thr);
    k_mask<<<(MAXACT*Dd + 255)/256, 256, 0, stream>>>(score, thr, sel, out_deg,
                                                      s1, s2, mxb, mnb, cnt, ctr);
    k_degree<<<(Ee + 255)/256, 256, 0, stream>>>(edge_index, sel, out_deg);
    k_active<<<(BN + 255)/256, 256, 0, stream>>>(out_deg, node_slot, alist, slot_deg,
                                                 ctr, flag, tlist);
    k_edges<<<(Ee + 255)/256, 256, 0, stream>>>(edge_index, sel, out_deg, node_slot,
                                                edges, cnt, ctr);
    k_messages<<<512, 128, 0, stream>>>(hidden, edges, alist, preWl, prebl,
                                        s1, s2, mxb, mnb, ctr);
    k_post<<<256, 512, 0, stream>>>(cnt, s1, s2, mxb, mnb, slot_deg, postWl, tpart, ctr);
    k_out_resid<<<MAXACT/32, 256, 0, stream>>>(tpart, alist, outWl, outbl, postbl,
                                               hidden, ctr);
    if (l < Ll-1){
      k_score<<<MAXTOUCH/32, 256, 0, stream>>>(hidden, cvec, lin_W, m1_W, m1_b, m2_W, m2_b,
                                               tlist, ctr, score, tlist, 0);
    } else {
      k_score<<<1, 256, 0, stream>>>(hidden, cvec, lin_W, m1_W, m1_b, m2_W, m2_b,
                                     tlist, ctr, score, hdr + 4, Bq*NEG);
    }
  }
  k_gather<<<1, 64, 0, stream>>>(score, hdr, (float*)d_out);
}